// Round 7
// baseline (821.061 us; speedup 1.0000x reference)
//
#include <hip/hip_runtime.h>
#include <math.h>

// ---------------------------------------------------------------------------
// LearnableWeightedRGCN — round 4.
// Key changes vs R3:
//  * attn-scaling moved OUT of the mega-GEMM: scores computed edge-wise from
//    y[n][r]=x[n]·w~[r] BEFORE aggregation; agg_csr stores attn-scaled bf16.
//    -> GEMM needs one accumulator (64 AGPR, was 128) -> 3x occupancy.
//  * GEMM restructured: 128x256 tile, 8 waves, BK=64, global_load_lds(16B)
//    staging with XOR-(row&7) source pre-swizzle, 2-barrier loop (m97-style).
//  * conv_emb: node_emb -> bf16 A-matrix + f32 x_all output in one pass.
// ---------------------------------------------------------------------------

typedef __attribute__((ext_vector_type(8))) short bf16x8;
typedef __attribute__((ext_vector_type(4))) float f32x4;
typedef unsigned long long u64;

__device__ __forceinline__ float gelu_exact(float v) {
    return 0.5f * v * (1.0f + erff(v * 0.70710678118654752f));
}
__device__ __forceinline__ unsigned short f2bf(float f) {   // RNE
    unsigned u = __float_as_uint(f);
    return (unsigned short)((u + 0x7fffu + ((u >> 16) & 1u)) >> 16);
}
__device__ __forceinline__ unsigned pack2(float a, float b) {
    return (unsigned)f2bf(a) | ((unsigned)f2bf(b) << 16);
}
__device__ __forceinline__ void gload16(const void* g, void* l) {
    __builtin_amdgcn_global_load_lds(
        (const __attribute__((address_space(1))) void*)g,
        (__attribute__((address_space(3))) void*)l, 16, 0, 0);
}

// ---------------------------------------------------------------------------
// node_emb f32 -> bf16 EMB  +  f32 x_all passthrough (fused copy)
// ---------------------------------------------------------------------------
__global__ __launch_bounds__(256)
void conv_emb(const float* __restrict__ ne, unsigned short* __restrict__ emb,
              float* __restrict__ outX, int total4)
{
    const int stride = gridDim.x * blockDim.x;
    for (int i = blockIdx.x * blockDim.x + threadIdx.x; i < total4; i += stride) {
        const float4 v = reinterpret_cast<const float4*>(ne)[i];
        reinterpret_cast<float4*>(outX)[i] = v;
        ushort4 h;
        h.x = f2bf(v.x); h.y = f2bf(v.y); h.z = f2bf(v.z); h.w = f2bf(v.w);
        reinterpret_cast<ushort4*>(emb)[i] = h;
    }
}

// ---------------------------------------------------------------------------
// B-matrix prep: BTm[n][k] (k<1024: rel_W[k>>8][k&255][n], else self_W),
// BTp[n][k] = pre_W[k][n]; both bf16.
// ---------------------------------------------------------------------------
__global__ __launch_bounds__(256)
void build_bt(const float* __restrict__ relW, const float* __restrict__ selfW,
              const float* __restrict__ preW, unsigned short* __restrict__ BTm,
              unsigned short* __restrict__ BTp)
{
    const int idx = blockIdx.x * 256 + threadIdx.x;
    if (idx < 1280 * 256) {
        const int k = idx >> 8, n = idx & 255;
        const float v = (k < 1024)
            ? relW[(size_t)(k >> 8) * 65536 + (size_t)(k & 255) * 256 + n]
            : selfW[(size_t)(k - 1024) * 256 + n];
        BTm[(size_t)n * 1280 + k] = f2bf(v);
    } else {
        const int i2 = idx - 1280 * 256;
        if (i2 < 256 * 256) {
            const int k = i2 >> 8, n = i2 & 255;
            BTp[(size_t)n * 256 + k] = f2bf(preW[(size_t)k * 256 + n]);
        }
    }
}

// ---------------------------------------------------------------------------
// MFMA GEMM: BM=128, BN=256, BK=64, 512 threads (8 waves, 2m x 4n), each
// wave -> 64x64 output (4x4 fragments of 16x16x32 bf16).
// Staging: global_load_lds dwordx4; LDS linear [row][128B], logical granule
// g stored at physical g^(row&7) via source pre-swizzle (read applies same).
// MODE 0: A=EMB bf16, K=256,  C = bf16 gelu(LN1(.+pre_b)) -> XOut
// MODE 1: A=[scaled agg r0..r3 | x] bf16 (5 segment pointers), K=1280,
//         C = f32 LN2(gelu(. + bias + self_b)) -> Cout
// ---------------------------------------------------------------------------
template<int MODE>
__global__ __launch_bounds__(512)
void gemm_mfma(const unsigned short* __restrict__ a0,
               const unsigned short* __restrict__ a1,
               const unsigned short* __restrict__ a2,
               const unsigned short* __restrict__ a3,
               const unsigned short* __restrict__ a4,
               const unsigned short* __restrict__ BT,
               const float* __restrict__ bias0, const float* __restrict__ bias1,
               const float* __restrict__ lng, const float* __restrict__ lnb,
               float* __restrict__ Cout, unsigned short* __restrict__ XOut,
               int M)
{
    constexpr int K    = MODE ? 1280 : 256;
    constexpr int NSEG = MODE ? 5 : 1;

    __shared__ __align__(16) unsigned char smA[128 * 128];   // 16 KB
    __shared__ __align__(16) unsigned char smB[256 * 128];   // 32 KB
    __shared__ float redS[4][128];
    __shared__ float redQ[4][128];

    const int tid = threadIdx.x;
    const int w   = tid >> 6;
    const int l   = tid & 63;
    const int wm  = w >> 2, wn = w & 3;
    const int brow = blockIdx.x * 128;

    const int srow = l >> 3;                 // row within 8-row chunk
    const int sgA  = (l & 7) ^ srow;         // pre-swizzled logical granule

    f32x4 acc[4][4];
#pragma unroll
    for (int mb = 0; mb < 4; ++mb)
#pragma unroll
        for (int nb = 0; nb < 4; ++nb)
            acc[mb][nb] = f32x4{0.f, 0.f, 0.f, 0.f};

    for (int seg = 0; seg < NSEG; ++seg) {
        const unsigned short* Abase =
            (MODE == 0) ? a0
                        : (seg == 0 ? a0 : seg == 1 ? a1 : seg == 2 ? a2
                                         : seg == 3 ? a3 : a4);
#pragma unroll
        for (int kk = 0; kk < 4; ++kk) {
            __syncthreads();     // all waves done reading previous tile
            // ---- A tile: 2 calls/wave, 8 rows each ----
#pragma unroll
            for (int c = 0; c < 2; ++c) {
                const int r0 = (w * 2 + c) * 8;
                int gm = brow + r0 + srow;
                gm = min(gm, M - 1);
                gload16(Abase + ((size_t)gm << 8) + kk * 64 + sgA * 8,
                        smA + (w * 2 + c) * 1024);
            }
            // ---- B tile: 4 calls/wave ----
#pragma unroll
            for (int c = 0; c < 4; ++c) {
                const int bn = (w * 4 + c) * 8 + srow;
                gload16(BT + (size_t)bn * K + (seg * 4 + kk) * 64 + sgA * 8,
                        smB + (w * 4 + c) * 1024);
            }
            __syncthreads();     // vmcnt drained -> tile visible

#pragma unroll
            for (int ks = 0; ks < 2; ++ks) {
                bf16x8 af[4], bf[4];
#pragma unroll
                for (int mb = 0; mb < 4; ++mb) {
                    const int row = wm * 64 + mb * 16 + (l & 15);
                    const int g   = (ks * 4 + (l >> 4)) ^ (row & 7);
                    af[mb] = *reinterpret_cast<const bf16x8*>(smA + row * 128 + g * 16);
                }
#pragma unroll
                for (int nb = 0; nb < 4; ++nb) {
                    const int row = wn * 64 + nb * 16 + (l & 15);
                    const int g   = (ks * 4 + (l >> 4)) ^ (row & 7);
                    bf[nb] = *reinterpret_cast<const bf16x8*>(smB + row * 128 + g * 16);
                }
#pragma unroll
                for (int mb = 0; mb < 4; ++mb)
#pragma unroll
                    for (int nb = 0; nb < 4; ++nb)
                        acc[mb][nb] = __builtin_amdgcn_mfma_f32_16x16x32_bf16(
                            af[mb], bf[nb], acc[mb][nb], 0, 0, 0);
            }
        }
    }

    // ---- epilogue: bias (+gelu for mode1), LN over 256 cols, store ----
    float bb[4], gw[4], bw[4];
#pragma unroll
    for (int nb = 0; nb < 4; ++nb) {
        const int n = wn * 64 + nb * 16 + (l & 15);
        bb[nb] = bias0[n] + (MODE == 1 ? bias1[n] : 0.0f);
        gw[nb] = lng[n];
        bw[nb] = lnb[n];
    }
#pragma unroll
    for (int mb = 0; mb < 4; ++mb)
#pragma unroll
        for (int nb = 0; nb < 4; ++nb)
#pragma unroll
            for (int rg = 0; rg < 4; ++rg) {
                float v = acc[mb][nb][rg] + bb[nb];
                if (MODE == 1) v = gelu_exact(v);
                acc[mb][nb][rg] = v;
            }
#pragma unroll
    for (int mb = 0; mb < 4; ++mb)
#pragma unroll
        for (int rg = 0; rg < 4; ++rg) {
            float s = 0.f, q = 0.f;
#pragma unroll
            for (int nb = 0; nb < 4; ++nb) {
                const float v = acc[mb][nb][rg];
                s += v; q += v * v;
            }
#pragma unroll
            for (int off = 1; off < 16; off <<= 1) {
                s += __shfl_xor(s, off, 64);
                q += __shfl_xor(q, off, 64);
            }
            if ((l & 15) == 0) {
                const int row = wm * 64 + mb * 16 + (l >> 4) * 4 + rg;
                redS[wn][row] = s;
                redQ[wn][row] = q;
            }
        }
    __syncthreads();
    if (tid < 128) {
        const float s = redS[0][tid] + redS[1][tid] + redS[2][tid] + redS[3][tid];
        const float q = redQ[0][tid] + redQ[1][tid] + redQ[2][tid] + redQ[3][tid];
        const float mean = s * (1.0f / 256.0f);
        const float var  = q * (1.0f / 256.0f) - mean * mean;
        redS[0][tid] = mean;
        redQ[0][tid] = rsqrtf(var + 1e-5f);
    }
    __syncthreads();
#pragma unroll
    for (int mb = 0; mb < 4; ++mb)
#pragma unroll
        for (int rg = 0; rg < 4; ++rg) {
            const int row = wm * 64 + mb * 16 + (l >> 4) * 4 + rg;
            if (brow + row >= M) continue;
            const float mu = redS[0][row];
            const float rs = redQ[0][row];
#pragma unroll
            for (int nb = 0; nb < 4; ++nb) {
                const int n = wn * 64 + nb * 16 + (l & 15);
                const float v = (acc[mb][nb][rg] - mu) * rs * gw[nb] + bw[nb];
                if (MODE == 0)
                    XOut[((size_t)(brow + row) << 8) + n] = f2bf(gelu_exact(v));
                else
                    Cout[((size_t)(brow + row) << 8) + n] = v;
            }
        }
}

// ---------------------------------------------------------------------------
// w~[r][k] = sum_j rel_W[r][k][j] * attn_vec[j]   (fp32)
// ---------------------------------------------------------------------------
__global__ __launch_bounds__(256)
void wtilde_kernel(const float* __restrict__ relW, const float* __restrict__ av,
                   float* __restrict__ wt)
{
    __shared__ float avs[256];
    const int r = blockIdx.x, tid = threadIdx.x;
    avs[tid] = av[tid];
    __syncthreads();
    const float* W = relW + (size_t)r * 65536 + (size_t)tid * 256;
    float s = 0.f;
    for (int j = 0; j < 256; j += 4) {
        const float4 w4 = *reinterpret_cast<const float4*>(W + j);
        s += w4.x * avs[j] + w4.y * avs[j + 1] + w4.z * avs[j + 2] + w4.w * avs[j + 3];
    }
    wt[r * 256 + tid] = s;
}

// ---------------------------------------------------------------------------
// y[n][r] = x[n] . w~[r]  — one wave per node.
// ---------------------------------------------------------------------------
__global__ __launch_bounds__(256)
void y_kernel(const unsigned short* __restrict__ XB, const float* __restrict__ wt,
              float* __restrict__ y, int Nn)
{
    const int n = blockIdx.x * 4 + (threadIdx.x >> 6);
    if (n >= Nn) return;
    const int l = threadIdx.x & 63;
    const uint2 d = *reinterpret_cast<const uint2*>(XB + ((size_t)n << 8) + l * 4);
    float xv[4];
    xv[0] = __uint_as_float(d.x << 16);
    xv[1] = __uint_as_float(d.x & 0xffff0000u);
    xv[2] = __uint_as_float(d.y << 16);
    xv[3] = __uint_as_float(d.y & 0xffff0000u);
    float s[4];
#pragma unroll
    for (int r = 0; r < 4; ++r) {
        const float4 w4 = *reinterpret_cast<const float4*>(wt + r * 256 + l * 4);
        s[r] = xv[0] * w4.x + xv[1] * w4.y + xv[2] * w4.z + xv[3] * w4.w;
#pragma unroll
        for (int off = 32; off; off >>= 1) s[r] += __shfl_xor(s[r], off, 64);
    }
    if (l == 0)
        *reinterpret_cast<float4*>(y + (size_t)n * 4) = make_float4(s[0], s[1], s[2], s[3]);
}

// ---------------------------------------------------------------------------
// CSR build (unchanged)
// ---------------------------------------------------------------------------
__global__ __launch_bounds__(256)
void hist_rows(const int* __restrict__ rows, int* __restrict__ counts,
               int RE, int E, int Nn)
{
    const int stride = gridDim.x * blockDim.x;
    for (int e = blockIdx.x * blockDim.x + threadIdx.x; e < RE; e += stride) {
        const int r = e / E;
        atomicAdd(&counts[r * Nn + rows[e]], 1);
    }
}

__global__ __launch_bounds__(256)
void scan_blocks(const int* __restrict__ counts, int* __restrict__ offs,
                 int* __restrict__ bsums, int n)
{
    __shared__ int sh[256];
    const int t = threadIdx.x;
    const int base = blockIdx.x * 1024 + t * 4;
    int v[4], s = 0;
#pragma unroll
    for (int j = 0; j < 4; ++j) {
        v[j] = (base + j < n) ? counts[base + j] : 0;
        s += v[j];
    }
    sh[t] = s;
    __syncthreads();
    for (int off = 1; off < 256; off <<= 1) {
        const int x = (t >= off) ? sh[t - off] : 0;
        __syncthreads();
        sh[t] += x;
        __syncthreads();
    }
    int run = sh[t] - s;
    if (t == 255) bsums[blockIdx.x] = sh[255];
#pragma unroll
    for (int j = 0; j < 4; ++j) {
        if (base + j < n) offs[base + j] = run;
        run += v[j];
    }
}

__global__ __launch_bounds__(256)
void scan_bsums(int* __restrict__ bsums, int nblk)
{
    __shared__ int sh[256];
    const int t = threadIdx.x;
    const int v = (t < nblk) ? bsums[t] : 0;
    sh[t] = v;
    __syncthreads();
    for (int off = 1; off < 256; off <<= 1) {
        const int x = (t >= off) ? sh[t - off] : 0;
        __syncthreads();
        sh[t] += x;
        __syncthreads();
    }
    if (t < nblk) bsums[t] = sh[t] - v;
}

__global__ __launch_bounds__(256)
void scan_add(int* __restrict__ offs, int* __restrict__ cursor,
              const int* __restrict__ bsums, int n)
{
    const int i = blockIdx.x * 256 + threadIdx.x;
    if (i >= n) return;
    const int v = offs[i] + bsums[i >> 10];
    offs[i]   = v;
    cursor[i] = v;
}

__global__ __launch_bounds__(256)
void scatter_edges(const int* __restrict__ rows, const int* __restrict__ cols,
                   const float* __restrict__ vals, int* __restrict__ cursor,
                   u64* __restrict__ edata, int RE, int E, int Nn)
{
    const int stride = gridDim.x * blockDim.x;
    for (int e = blockIdx.x * blockDim.x + threadIdx.x; e < RE; e += stride) {
        const int r   = e / E;
        const int pos = atomicAdd(&cursor[r * Nn + rows[e]], 1);
        edata[pos] = ((u64)__float_as_uint(vals[e]) << 32) | (unsigned)cols[e];
    }
}

// ---------------------------------------------------------------------------
// Edge-wise scores: score[n][r] = sum val * y[col][r]; sentinel if deg==0.
// One thread per (r,n).
// ---------------------------------------------------------------------------
__global__ __launch_bounds__(256)
void score_csr(const int* __restrict__ offs, const u64* __restrict__ edata,
               const float* __restrict__ y, float* __restrict__ scores,
               int Nn, int RE)
{
    const int wid = blockIdx.x * 256 + threadIdx.x;
    const int RN  = Nn << 2;
    if (wid >= RN) return;
    const int r = wid / Nn;
    const int n = wid - r * Nn;
    const int start = offs[wid];
    const int end   = (wid + 1 < RN) ? offs[wid + 1] : RE;

    float s = 0.f;
    int j = start;
    for (; j + 3 < end; j += 4) {
        u64 e[4];
        float yv[4], vv[4];
#pragma unroll
        for (int q = 0; q < 4; ++q) e[q] = edata[j + q];
#pragma unroll
        for (int q = 0; q < 4; ++q) {
            vv[q] = __uint_as_float((unsigned)(e[q] >> 32));
            yv[q] = y[((size_t)(unsigned)(e[q] & 0xffffffffu)) * 4 + r];
        }
#pragma unroll
        for (int q = 0; q < 4; ++q) s = fmaf(vv[q], yv[q], s);
    }
    for (; j < end; ++j) {
        const u64 e0 = edata[j];
        s = fmaf(__uint_as_float((unsigned)(e0 >> 32)),
                 y[((size_t)(unsigned)(e0 & 0xffffffffu)) * 4 + r], s);
    }
    scores[(size_t)n * 4 + r] = (end > start) ? s : -1e30f;
}

// ---------------------------------------------------------------------------
// Per-node masked softmax over 4 relation scores.
// ---------------------------------------------------------------------------
__global__ __launch_bounds__(256)
void softmax4(const float* __restrict__ scores, float* __restrict__ attn, int Nn)
{
    const int n = blockIdx.x * 256 + threadIdx.x;
    if (n >= Nn) return;
    const float4 s4 = *reinterpret_cast<const float4*>(scores + (size_t)n * 4);
    float s[4] = { s4.x, s4.y, s4.z, s4.w };
    float mx = -3.0e38f;
#pragma unroll
    for (int r = 0; r < 4; ++r) mx = fmaxf(mx, s[r]);
    float ex[4], es = 0.f;
#pragma unroll
    for (int r = 0; r < 4; ++r) { ex[r] = expf(s[r] - mx); es += ex[r]; }
    const float inv = 1.0f / es;
    float4 o;
    o.x = (s[0] > -1e29f) ? ex[0] * inv : 0.0f;
    o.y = (s[1] > -1e29f) ? ex[1] * inv : 0.0f;
    o.z = (s[2] > -1e29f) ? ex[2] * inv : 0.0f;
    o.w = (s[3] > -1e29f) ? ex[3] * inv : 0.0f;
    *reinterpret_cast<float4*>(attn + (size_t)n * 4) = o;
}

// ---------------------------------------------------------------------------
// Aggregation: one wave per (r,n). bf16 gather, f32 acc, attn-scaled bf16
// store (scale known because scores were computed edge-wise beforehand).
// ---------------------------------------------------------------------------
__global__ __launch_bounds__(256)
void agg_csr(const int* __restrict__ offs, const u64* __restrict__ edata,
             const unsigned short* __restrict__ x, const float* __restrict__ attn,
             unsigned short* __restrict__ agg, int Nn, int RE)
{
    const int wid  = (blockIdx.x << 2) + (threadIdx.x >> 6);
    const int lane = threadIdx.x & 63;
    const int RN   = Nn << 2;
    if (wid >= RN) return;
    const int r = wid / Nn;
    const int n = wid - r * Nn;

    const int start = offs[wid];
    const int end   = (wid + 1 < RN) ? offs[wid + 1] : RE;

    float ax = 0.f, ay = 0.f, az = 0.f, aw = 0.f;
    int j = start;
    for (; j + 3 < end; j += 4) {
        u64 e[4];
        uint2 d[4];
        float v[4];
#pragma unroll
        for (int q = 0; q < 4; ++q) e[q] = edata[j + q];
#pragma unroll
        for (int q = 0; q < 4; ++q) {
            const int c = (int)(e[q] & 0xffffffffu);
            v[q] = __uint_as_float((unsigned)(e[q] >> 32));
            d[q] = *reinterpret_cast<const uint2*>(x + ((size_t)c << 8) + lane * 4);
        }
#pragma unroll
        for (int q = 0; q < 4; ++q) {
            ax = fmaf(v[q], __uint_as_float(d[q].x << 16),         ax);
            ay = fmaf(v[q], __uint_as_float(d[q].x & 0xffff0000u), ay);
            az = fmaf(v[q], __uint_as_float(d[q].y << 16),         az);
            aw = fmaf(v[q], __uint_as_float(d[q].y & 0xffff0000u), aw);
        }
    }
    for (; j < end; ++j) {
        const u64 e0 = edata[j];
        const int   c0 = (int)(e0 & 0xffffffffu);
        const float v0 = __uint_as_float((unsigned)(e0 >> 32));
        const uint2 d0 = *reinterpret_cast<const uint2*>(x + ((size_t)c0 << 8) + lane * 4);
        ax = fmaf(v0, __uint_as_float(d0.x << 16),         ax);
        ay = fmaf(v0, __uint_as_float(d0.x & 0xffff0000u), ay);
        az = fmaf(v0, __uint_as_float(d0.y << 16),         az);
        aw = fmaf(v0, __uint_as_float(d0.y & 0xffff0000u), aw);
    }

    const float sc = attn[(size_t)n * 4 + r];
    uint2 st;
    st.x = pack2(sc * ax, sc * ay);
    st.y = pack2(sc * az, sc * aw);
    *reinterpret_cast<uint2*>(agg + ((size_t)wid << 8) + lane * 4) = st;
}

// ---------------------------------------------------------------------------
extern "C" void kernel_launch(void* const* d_in, const int* in_sizes, int n_in,
                              void* d_out, int out_size, void* d_ws, size_t ws_size,
                              hipStream_t stream)
{
    const int*   rows     = (const int*)d_in[0];
    const int*   cols     = (const int*)d_in[1];
    const float* vals     = (const float*)d_in[2];
    const float* node_emb = (const float*)d_in[3];
    const float* pre_W    = (const float*)d_in[4];
    const float* pre_b    = (const float*)d_in[5];
    const float* ln1_g    = (const float*)d_in[6];
    const float* ln1_b    = (const float*)d_in[7];
    const float* rel_W    = (const float*)d_in[8];
    const float* attn_vec = (const float*)d_in[9];
    const float* self_W   = (const float*)d_in[10];
    const float* self_b   = (const float*)d_in[11];
    const float* bias     = (const float*)d_in[12];
    const float* ln2_g    = (const float*)d_in[13];
    const float* ln2_b    = (const float*)d_in[14];

    const int Dd = 256;
    const int R  = in_sizes[8] / (Dd * Dd);   // 4
    const int N  = in_sizes[3] / Dd;          // 50000
    const int E  = in_sizes[0] / R;           // 800000
    const int RE = R * E;
    const int RN = R * N;

    float* out  = (float*)d_out;
    float* outF = out;                              // final  [N][256] f32
    float* outA = out + (size_t)N * Dd;             // attn   [N][4]   f32
    float* outX = outA + (size_t)N * R;             // x_all  [N][256] f32

    char* wp = (char*)d_ws;
    auto alloc = [&](size_t bytes) {
        char* p = wp;
        wp += (bytes + 255) & ~(size_t)255;
        return p;
    };
    unsigned short* AGGS = (unsigned short*)alloc((size_t)RN * Dd * 2);   // 102.4 MB
    unsigned short* XB   = (unsigned short*)alloc((size_t)N * Dd * 2);    //  25.6 MB
    unsigned short* EMB  = (unsigned short*)alloc((size_t)N * Dd * 2);    //  25.6 MB
    unsigned short* BTm  = (unsigned short*)alloc((size_t)Dd * 1280 * 2); // 655 KB
    unsigned short* BTp  = (unsigned short*)alloc((size_t)Dd * Dd * 2);   // 131 KB
    float* WT  = (float*)alloc((size_t)R * Dd * 4);
    float* Y   = (float*)alloc((size_t)N * R * 4);
    float* SC  = (float*)alloc((size_t)N * R * 4);
    int* counts = (int*)alloc((size_t)RN * 4);
    int* offs   = (int*)alloc((size_t)RN * 4);
    int* cursor = (int*)alloc((size_t)RN * 4);
    int* bsums  = (int*)alloc(1024);
    u64* edata  = (u64*)alloc((size_t)RE * 8);                            // 25.6 MB

    const int gblocks = (N + 127) / 128;            // 391
    const int nblk    = (RN + 1023) / 1024;         // 196

    // 1. B-matrix prep + emb conversion (+x_all passthrough)
    build_bt<<<(1280 * 256 + 256 * 256 + 255) / 256, 256, 0, stream>>>(
        rel_W, self_W, pre_W, BTm, BTp);
    conv_emb<<<2048, 256, 0, stream>>>(node_emb, EMB, outX, N * Dd / 4);

    // 2. pre-encoder -> X bf16
    gemm_mfma<0><<<gblocks, 512, 0, stream>>>(EMB, nullptr, nullptr, nullptr, nullptr,
                                              BTp, pre_b, nullptr, ln1_g, ln1_b,
                                              nullptr, XB, N);
    // 3. w~ and y
    wtilde_kernel<<<R, 256, 0, stream>>>(rel_W, attn_vec, WT);
    y_kernel<<<(N + 3) / 4, 256, 0, stream>>>(XB, WT, Y, N);

    // 4. CSR build
    hipMemsetAsync(counts, 0, (size_t)RN * sizeof(int), stream);
    hist_rows<<<2048, 256, 0, stream>>>(rows, counts, RE, E, N);
    scan_blocks<<<nblk, 256, 0, stream>>>(counts, offs, bsums, RN);
    scan_bsums<<<1, 256, 0, stream>>>(bsums, nblk);
    scan_add<<<(RN + 255) / 256, 256, 0, stream>>>(offs, cursor, bsums, RN);
    scatter_edges<<<2048, 256, 0, stream>>>(rows, cols, vals, cursor, edata, RE, E, N);

    // 5. edge-wise scores -> masked softmax -> attn (outA)
    score_csr<<<(RN + 255) / 256, 256, 0, stream>>>(offs, edata, Y, SC, N, RE);
    softmax4<<<(N + 255) / 256, 256, 0, stream>>>(SC, outA, N);

    // 6. aggregation with fused attn scaling
    agg_csr<<<(RN + 3) / 4, 256, 0, stream>>>(offs, edata, XB, outA, AGGS, N, RE);

    // 7. mega-GEMM -> final (outF)
    gemm_mfma<1><<<gblocks, 512, 0, stream>>>(AGGS, AGGS + (size_t)N * Dd,
                                              AGGS + (size_t)2 * N * Dd,
                                              AGGS + (size_t)3 * N * Dd, XB,
                                              BTm, bias, self_b, ln2_g, ln2_b,
                                              outF, nullptr, N);
}

// Round 8
// 671.827 us; speedup vs baseline: 1.2221x; 1.2221x over previous
//
#include <hip/hip_runtime.h>
#include <math.h>

// ---------------------------------------------------------------------------
// LearnableWeightedRGCN — round 8.
// Change vs R7: two-level scatter (coarse bins -> fine) kills the 198 MB
// partial-line write-allocate storm of the single-pass scatter.
//   hist_widbin: per-wid global hist (offs) + per-(block,bin) hist (coarse)
//   scan(counts) -> offs ; scan(cnt_t) -> ctoffs
//   scatter_coarse: edges -> block-private bin regions (LDS cursors)
//   scatter_fine: bin-exclusive block -> exact per-wid position (LDS cursors)
// Rest of pipeline unchanged from R7.
// ---------------------------------------------------------------------------

typedef __attribute__((ext_vector_type(8))) short bf16x8;
typedef __attribute__((ext_vector_type(4))) float f32x4;
typedef unsigned long long u64;

__device__ __forceinline__ float gelu_exact(float v) {
    return 0.5f * v * (1.0f + erff(v * 0.70710678118654752f));
}
__device__ __forceinline__ unsigned short f2bf(float f) {   // RNE
    unsigned u = __float_as_uint(f);
    return (unsigned short)((u + 0x7fffu + ((u >> 16) & 1u)) >> 16);
}
__device__ __forceinline__ unsigned pack2(float a, float b) {
    return (unsigned)f2bf(a) | ((unsigned)f2bf(b) << 16);
}
__device__ __forceinline__ void gload16(const void* g, void* l) {
    __builtin_amdgcn_global_load_lds(
        (const __attribute__((address_space(1))) void*)g,
        (__attribute__((address_space(3))) void*)l, 16, 0, 0);
}

// ---------------------------------------------------------------------------
// node_emb f32 -> bf16 EMB  +  f32 x_all passthrough (fused copy)
// ---------------------------------------------------------------------------
__global__ __launch_bounds__(256)
void conv_emb(const float* __restrict__ ne, unsigned short* __restrict__ emb,
              float* __restrict__ outX, int total4)
{
    const int stride = gridDim.x * blockDim.x;
    for (int i = blockIdx.x * blockDim.x + threadIdx.x; i < total4; i += stride) {
        const float4 v = reinterpret_cast<const float4*>(ne)[i];
        reinterpret_cast<float4*>(outX)[i] = v;
        ushort4 h;
        h.x = f2bf(v.x); h.y = f2bf(v.y); h.z = f2bf(v.z); h.w = f2bf(v.w);
        reinterpret_cast<ushort4*>(emb)[i] = h;
    }
}

// ---------------------------------------------------------------------------
// B-matrix prep: BTm[n][k] (k<1024: rel_W[k>>8][k&255][n], else self_W),
// BTp[n][k] = pre_W[k][n]; both bf16.
// ---------------------------------------------------------------------------
__global__ __launch_bounds__(256)
void build_bt(const float* __restrict__ relW, const float* __restrict__ selfW,
              const float* __restrict__ preW, unsigned short* __restrict__ BTm,
              unsigned short* __restrict__ BTp)
{
    const int idx = blockIdx.x * 256 + threadIdx.x;
    if (idx < 1280 * 256) {
        const int k = idx >> 8, n = idx & 255;
        const float v = (k < 1024)
            ? relW[(size_t)(k >> 8) * 65536 + (size_t)(k & 255) * 256 + n]
            : selfW[(size_t)(k - 1024) * 256 + n];
        BTm[(size_t)n * 1280 + k] = f2bf(v);
    } else {
        const int i2 = idx - 1280 * 256;
        if (i2 < 256 * 256) {
            const int k = i2 >> 8, n = i2 & 255;
            BTp[(size_t)n * 256 + k] = f2bf(preW[(size_t)k * 256 + n]);
        }
    }
}

// ---------------------------------------------------------------------------
// MFMA GEMM: BM=128, BN=256, BK=64, 512 threads (8 waves, 2m x 4n).
// (unchanged from R7)
// ---------------------------------------------------------------------------
template<int MODE>
__global__ __launch_bounds__(512)
void gemm_mfma(const unsigned short* __restrict__ a0,
               const unsigned short* __restrict__ a1,
               const unsigned short* __restrict__ a2,
               const unsigned short* __restrict__ a3,
               const unsigned short* __restrict__ a4,
               const unsigned short* __restrict__ BT,
               const float* __restrict__ bias0, const float* __restrict__ bias1,
               const float* __restrict__ lng, const float* __restrict__ lnb,
               float* __restrict__ Cout, unsigned short* __restrict__ XOut,
               int M)
{
    constexpr int K    = MODE ? 1280 : 256;
    constexpr int NSEG = MODE ? 5 : 1;

    __shared__ __align__(16) unsigned char smA[128 * 128];   // 16 KB
    __shared__ __align__(16) unsigned char smB[256 * 128];   // 32 KB
    __shared__ float redS[4][128];
    __shared__ float redQ[4][128];

    const int tid = threadIdx.x;
    const int w   = tid >> 6;
    const int l   = tid & 63;
    const int wm  = w >> 2, wn = w & 3;
    const int brow = blockIdx.x * 128;

    const int srow = l >> 3;
    const int sgA  = (l & 7) ^ srow;

    f32x4 acc[4][4];
#pragma unroll
    for (int mb = 0; mb < 4; ++mb)
#pragma unroll
        for (int nb = 0; nb < 4; ++nb)
            acc[mb][nb] = f32x4{0.f, 0.f, 0.f, 0.f};

    for (int seg = 0; seg < NSEG; ++seg) {
        const unsigned short* Abase =
            (MODE == 0) ? a0
                        : (seg == 0 ? a0 : seg == 1 ? a1 : seg == 2 ? a2
                                         : seg == 3 ? a3 : a4);
#pragma unroll
        for (int kk = 0; kk < 4; ++kk) {
            __syncthreads();
#pragma unroll
            for (int c = 0; c < 2; ++c) {
                const int r0 = (w * 2 + c) * 8;
                int gm = brow + r0 + srow;
                gm = min(gm, M - 1);
                gload16(Abase + ((size_t)gm << 8) + kk * 64 + sgA * 8,
                        smA + (w * 2 + c) * 1024);
            }
#pragma unroll
            for (int c = 0; c < 4; ++c) {
                const int bn = (w * 4 + c) * 8 + srow;
                gload16(BT + (size_t)bn * K + (seg * 4 + kk) * 64 + sgA * 8,
                        smB + (w * 4 + c) * 1024);
            }
            __syncthreads();

#pragma unroll
            for (int ks = 0; ks < 2; ++ks) {
                bf16x8 af[4], bf[4];
#pragma unroll
                for (int mb = 0; mb < 4; ++mb) {
                    const int row = wm * 64 + mb * 16 + (l & 15);
                    const int g   = (ks * 4 + (l >> 4)) ^ (row & 7);
                    af[mb] = *reinterpret_cast<const bf16x8*>(smA + row * 128 + g * 16);
                }
#pragma unroll
                for (int nb = 0; nb < 4; ++nb) {
                    const int row = wn * 64 + nb * 16 + (l & 15);
                    const int g   = (ks * 4 + (l >> 4)) ^ (row & 7);
                    bf[nb] = *reinterpret_cast<const bf16x8*>(smB + row * 128 + g * 16);
                }
#pragma unroll
                for (int mb = 0; mb < 4; ++mb)
#pragma unroll
                    for (int nb = 0; nb < 4; ++nb)
                        acc[mb][nb] = __builtin_amdgcn_mfma_f32_16x16x32_bf16(
                            af[mb], bf[nb], acc[mb][nb], 0, 0, 0);
            }
        }
    }

    // ---- epilogue ----
    float bb[4], gw[4], bw[4];
#pragma unroll
    for (int nb = 0; nb < 4; ++nb) {
        const int n = wn * 64 + nb * 16 + (l & 15);
        bb[nb] = bias0[n] + (MODE == 1 ? bias1[n] : 0.0f);
        gw[nb] = lng[n];
        bw[nb] = lnb[n];
    }
#pragma unroll
    for (int mb = 0; mb < 4; ++mb)
#pragma unroll
        for (int nb = 0; nb < 4; ++nb)
#pragma unroll
            for (int rg = 0; rg < 4; ++rg) {
                float v = acc[mb][nb][rg] + bb[nb];
                if (MODE == 1) v = gelu_exact(v);
                acc[mb][nb][rg] = v;
            }
#pragma unroll
    for (int mb = 0; mb < 4; ++mb)
#pragma unroll
        for (int rg = 0; rg < 4; ++rg) {
            float s = 0.f, q = 0.f;
#pragma unroll
            for (int nb = 0; nb < 4; ++nb) {
                const float v = acc[mb][nb][rg];
                s += v; q += v * v;
            }
#pragma unroll
            for (int off = 1; off < 16; off <<= 1) {
                s += __shfl_xor(s, off, 64);
                q += __shfl_xor(q, off, 64);
            }
            if ((l & 15) == 0) {
                const int row = wm * 64 + mb * 16 + (l >> 4) * 4 + rg;
                redS[wn][row] = s;
                redQ[wn][row] = q;
            }
        }
    __syncthreads();
    if (tid < 128) {
        const float s = redS[0][tid] + redS[1][tid] + redS[2][tid] + redS[3][tid];
        const float q = redQ[0][tid] + redQ[1][tid] + redQ[2][tid] + redQ[3][tid];
        const float mean = s * (1.0f / 256.0f);
        const float var  = q * (1.0f / 256.0f) - mean * mean;
        redS[0][tid] = mean;
        redQ[0][tid] = rsqrtf(var + 1e-5f);
    }
    __syncthreads();
#pragma unroll
    for (int mb = 0; mb < 4; ++mb)
#pragma unroll
        for (int rg = 0; rg < 4; ++rg) {
            const int row = wm * 64 + mb * 16 + (l >> 4) * 4 + rg;
            if (brow + row >= M) continue;
            const float mu = redS[0][row];
            const float rs = redQ[0][row];
#pragma unroll
            for (int nb = 0; nb < 4; ++nb) {
                const int n = wn * 64 + nb * 16 + (l & 15);
                const float v = (acc[mb][nb][rg] - mu) * rs * gw[nb] + bw[nb];
                if (MODE == 0)
                    XOut[((size_t)(brow + row) << 8) + n] = f2bf(gelu_exact(v));
                else
                    Cout[((size_t)(brow + row) << 8) + n] = v;
            }
        }
}

// ---------------------------------------------------------------------------
// w~[r][k] = sum_j rel_W[r][k][j] * attn_vec[j]   (fp32)
// ---------------------------------------------------------------------------
__global__ __launch_bounds__(256)
void wtilde_kernel(const float* __restrict__ relW, const float* __restrict__ av,
                   float* __restrict__ wt)
{
    __shared__ float avs[256];
    const int r = blockIdx.x, tid = threadIdx.x;
    avs[tid] = av[tid];
    __syncthreads();
    const float* W = relW + (size_t)r * 65536 + (size_t)tid * 256;
    float s = 0.f;
    for (int j = 0; j < 256; j += 4) {
        const float4 w4 = *reinterpret_cast<const float4*>(W + j);
        s += w4.x * avs[j] + w4.y * avs[j + 1] + w4.z * avs[j + 2] + w4.w * avs[j + 3];
    }
    wt[r * 256 + tid] = s;
}

// ---------------------------------------------------------------------------
// y[n][r] = x[n] . w~[r]  — one wave per node.
// ---------------------------------------------------------------------------
__global__ __launch_bounds__(256)
void y_kernel(const unsigned short* __restrict__ XB, const float* __restrict__ wt,
              float* __restrict__ y, int Nn)
{
    const int n = blockIdx.x * 4 + (threadIdx.x >> 6);
    if (n >= Nn) return;
    const int l = threadIdx.x & 63;
    const uint2 d = *reinterpret_cast<const uint2*>(XB + ((size_t)n << 8) + l * 4);
    float xv[4];
    xv[0] = __uint_as_float(d.x << 16);
    xv[1] = __uint_as_float(d.x & 0xffff0000u);
    xv[2] = __uint_as_float(d.y << 16);
    xv[3] = __uint_as_float(d.y & 0xffff0000u);
    float s[4];
#pragma unroll
    for (int r = 0; r < 4; ++r) {
        const float4 w4 = *reinterpret_cast<const float4*>(wt + r * 256 + l * 4);
        s[r] = xv[0] * w4.x + xv[1] * w4.y + xv[2] * w4.z + xv[3] * w4.w;
#pragma unroll
        for (int off = 32; off; off >>= 1) s[r] += __shfl_xor(s[r], off, 64);
    }
    if (l == 0)
        *reinterpret_cast<float4*>(y + (size_t)n * 4) = make_float4(s[0], s[1], s[2], s[3]);
}

// ---------------------------------------------------------------------------
// Fused histogram: per-wid global counts (for offs scan) + per-(block,bin)
// counts cnt_t[bin*NB1+blk] (for coarse scatter regions). bin = wid>>8.
// Blocks own contiguous edge chunks (same mapping as scatter_coarse).
// ---------------------------------------------------------------------------
__global__ __launch_bounds__(256)
void hist_widbin(const int* __restrict__ rows, int* __restrict__ counts,
                 int* __restrict__ cnt_t, int RE, int E, int Nn,
                 int chunk, int NBIN)
{
    __shared__ int lh[800];
    const int blk = blockIdx.x;
    for (int i = threadIdx.x; i < NBIN; i += 256) lh[i] = 0;
    __syncthreads();
    const int e0 = blk * chunk;
    const int e1 = min(e0 + chunk, RE);
    for (int e = e0 + threadIdx.x; e < e1; e += 256) {
        const int r   = e / E;
        const int wid = r * Nn + rows[e];
        atomicAdd(&counts[wid], 1);
        atomicAdd(&lh[wid >> 8], 1);
    }
    __syncthreads();
    for (int i = threadIdx.x; i < NBIN; i += 256)
        cnt_t[i * gridDim.x + blk] = lh[i];
}

// ---------------------------------------------------------------------------
// Exclusive scan (generic, from R7): scan_blocks / scan_bsums / scan_add
// ---------------------------------------------------------------------------
__global__ __launch_bounds__(256)
void scan_blocks(const int* __restrict__ counts, int* __restrict__ offs,
                 int* __restrict__ bsums, int n)
{
    __shared__ int sh[256];
    const int t = threadIdx.x;
    const int base = blockIdx.x * 1024 + t * 4;
    int v[4], s = 0;
#pragma unroll
    for (int j = 0; j < 4; ++j) {
        v[j] = (base + j < n) ? counts[base + j] : 0;
        s += v[j];
    }
    sh[t] = s;
    __syncthreads();
    for (int off = 1; off < 256; off <<= 1) {
        const int x = (t >= off) ? sh[t - off] : 0;
        __syncthreads();
        sh[t] += x;
        __syncthreads();
    }
    int run = sh[t] - s;
    if (t == 255) bsums[blockIdx.x] = sh[255];
#pragma unroll
    for (int j = 0; j < 4; ++j) {
        if (base + j < n) offs[base + j] = run;
        run += v[j];
    }
}

__global__ __launch_bounds__(256)
void scan_bsums(int* __restrict__ bsums, int nblk)
{
    __shared__ int sh[256];
    const int t = threadIdx.x;
    const int v = (t < nblk) ? bsums[t] : 0;
    sh[t] = v;
    __syncthreads();
    for (int off = 1; off < 256; off <<= 1) {
        const int x = (t >= off) ? sh[t - off] : 0;
        __syncthreads();
        sh[t] += x;
        __syncthreads();
    }
    if (t < nblk) bsums[t] = sh[t] - v;
}

__global__ __launch_bounds__(256)
void scan_add(int* __restrict__ offs, const int* __restrict__ bsums, int n)
{
    const int i = blockIdx.x * 256 + threadIdx.x;
    if (i >= n) return;
    offs[i] += bsums[i >> 10];
}

// ---------------------------------------------------------------------------
// Coarse scatter: edges -> block-private per-bin regions (LDS cursors, no
// global atomics). Payload packs (val[31:2]|r, row<<16|col); val loses 2
// mantissa LSBs (2^-22 rel).
// ---------------------------------------------------------------------------
__global__ __launch_bounds__(256)
void scatter_coarse(const int* __restrict__ rows, const int* __restrict__ cols,
                    const float* __restrict__ vals, const int* __restrict__ ctoffs,
                    u64* __restrict__ edc, int RE, int E, int Nn,
                    int chunk, int NBIN)
{
    __shared__ int lcur[800];
    const int blk = blockIdx.x;
    for (int i = threadIdx.x; i < NBIN; i += 256)
        lcur[i] = ctoffs[i * gridDim.x + blk];
    __syncthreads();
    const int e0 = blk * chunk;
    const int e1 = min(e0 + chunk, RE);
    for (int e = e0 + threadIdx.x; e < e1; e += 256) {
        const int r   = e / E;
        const int row = rows[e];
        const int wid = r * Nn + row;
        const int pos = atomicAdd(&lcur[wid >> 8], 1);
        const unsigned vb = __float_as_uint(vals[e]);
        edc[pos] = ((u64)((vb & 0xFFFFFFFCu) | (unsigned)r) << 32)
                 | ((unsigned)row << 16) | (unsigned)cols[e];
    }
}

// ---------------------------------------------------------------------------
// Fine scatter: one block per bin (256 wids). Per-wid positions = offs held
// as LDS cursors (bin exclusive to this block -> no global atomics). Writes
// land in the bin's ~32 KB window, written by one XCD -> full-line evictions.
// ---------------------------------------------------------------------------
__global__ __launch_bounds__(256)
void scatter_fine(const u64* __restrict__ edc, const int* __restrict__ ctoffs,
                  const int* __restrict__ offs, u64* __restrict__ edata,
                  int RE, int Nn, int NB1, int NBIN)
{
    __shared__ int cur[256];
    const int bin     = blockIdx.x;
    const int widbase = bin << 8;
    const int RN      = Nn << 2;
    const int wid     = widbase + threadIdx.x;
    cur[threadIdx.x] = (wid < RN) ? offs[wid] : 0;
    __syncthreads();
    const int cs = ctoffs[bin * NB1];
    const int ce = (bin + 1 < NBIN) ? ctoffs[(bin + 1) * NB1] : RE;
    for (int j = cs + threadIdx.x; j < ce; j += 256) {
        const u64 p  = edc[j];
        const unsigned hi = (unsigned)(p >> 32);
        const unsigned lo = (unsigned)p;
        const int r   = (int)(hi & 3u);
        const int row = (int)(lo >> 16);
        const int w   = r * Nn + row;
        const int pos = atomicAdd(&cur[w - widbase], 1);
        edata[pos] = ((u64)(hi & 0xFFFFFFFCu) << 32) | (lo & 0xFFFFu);
    }
}

// ---------------------------------------------------------------------------
// Edge-wise scores: score[n][r] = sum val * y[col][r]; sentinel if deg==0.
// ---------------------------------------------------------------------------
__global__ __launch_bounds__(256)
void score_csr(const int* __restrict__ offs, const u64* __restrict__ edata,
               const float* __restrict__ y, float* __restrict__ scores,
               int Nn, int RE)
{
    const int wid = blockIdx.x * 256 + threadIdx.x;
    const int RN  = Nn << 2;
    if (wid >= RN) return;
    const int r = wid / Nn;
    const int n = wid - r * Nn;
    const int start = offs[wid];
    const int end   = (wid + 1 < RN) ? offs[wid + 1] : RE;

    float s = 0.f;
    int j = start;
    for (; j + 3 < end; j += 4) {
        u64 e[4];
        float yv[4], vv[4];
#pragma unroll
        for (int q = 0; q < 4; ++q) e[q] = edata[j + q];
#pragma unroll
        for (int q = 0; q < 4; ++q) {
            vv[q] = __uint_as_float((unsigned)(e[q] >> 32));
            yv[q] = y[((size_t)(unsigned)(e[q] & 0xffffffffu)) * 4 + r];
        }
#pragma unroll
        for (int q = 0; q < 4; ++q) s = fmaf(vv[q], yv[q], s);
    }
    for (; j < end; ++j) {
        const u64 e0 = edata[j];
        s = fmaf(__uint_as_float((unsigned)(e0 >> 32)),
                 y[((size_t)(unsigned)(e0 & 0xffffffffu)) * 4 + r], s);
    }
    scores[(size_t)n * 4 + r] = (end > start) ? s : -1e30f;
}

// ---------------------------------------------------------------------------
// Per-node masked softmax over 4 relation scores.
// ---------------------------------------------------------------------------
__global__ __launch_bounds__(256)
void softmax4(const float* __restrict__ scores, float* __restrict__ attn, int Nn)
{
    const int n = blockIdx.x * 256 + threadIdx.x;
    if (n >= Nn) return;
    const float4 s4 = *reinterpret_cast<const float4*>(scores + (size_t)n * 4);
    float s[4] = { s4.x, s4.y, s4.z, s4.w };
    float mx = -3.0e38f;
#pragma unroll
    for (int r = 0; r < 4; ++r) mx = fmaxf(mx, s[r]);
    float ex[4], es = 0.f;
#pragma unroll
    for (int r = 0; r < 4; ++r) { ex[r] = expf(s[r] - mx); es += ex[r]; }
    const float inv = 1.0f / es;
    float4 o;
    o.x = (s[0] > -1e29f) ? ex[0] * inv : 0.0f;
    o.y = (s[1] > -1e29f) ? ex[1] * inv : 0.0f;
    o.z = (s[2] > -1e29f) ? ex[2] * inv : 0.0f;
    o.w = (s[3] > -1e29f) ? ex[3] * inv : 0.0f;
    *reinterpret_cast<float4*>(attn + (size_t)n * 4) = o;
}

// ---------------------------------------------------------------------------
// Aggregation: one wave per (r,n). bf16 gather, f32 acc, attn-scaled bf16
// store. (unchanged from R7)
// ---------------------------------------------------------------------------
__global__ __launch_bounds__(256)
void agg_csr(const int* __restrict__ offs, const u64* __restrict__ edata,
             const unsigned short* __restrict__ x, const float* __restrict__ attn,
             unsigned short* __restrict__ agg, int Nn, int RE)
{
    const int wid  = (blockIdx.x << 2) + (threadIdx.x >> 6);
    const int lane = threadIdx.x & 63;
    const int RN   = Nn << 2;
    if (wid >= RN) return;
    const int r = wid / Nn;
    const int n = wid - r * Nn;

    const int start = offs[wid];
    const int end   = (wid + 1 < RN) ? offs[wid + 1] : RE;

    float ax = 0.f, ay = 0.f, az = 0.f, aw = 0.f;
    int j = start;
    for (; j + 3 < end; j += 4) {
        u64 e[4];
        uint2 d[4];
        float v[4];
#pragma unroll
        for (int q = 0; q < 4; ++q) e[q] = edata[j + q];
#pragma unroll
        for (int q = 0; q < 4; ++q) {
            const int c = (int)(e[q] & 0xffffffffu);
            v[q] = __uint_as_float((unsigned)(e[q] >> 32));
            d[q] = *reinterpret_cast<const uint2*>(x + ((size_t)c << 8) + lane * 4);
        }
#pragma unroll
        for (int q = 0; q < 4; ++q) {
            ax = fmaf(v[q], __uint_as_float(d[q].x << 16),         ax);
            ay = fmaf(v[q], __uint_as_float(d[q].x & 0xffff0000u), ay);
            az = fmaf(v[q], __uint_as_float(d[q].y << 16),         az);
            aw = fmaf(v[q], __uint_as_float(d[q].y & 0xffff0000u), aw);
        }
    }
    for (; j < end; ++j) {
        const u64 e0 = edata[j];
        const int   c0 = (int)(e0 & 0xffffffffu);
        const float v0 = __uint_as_float((unsigned)(e0 >> 32));
        const uint2 d0 = *reinterpret_cast<const uint2*>(x + ((size_t)c0 << 8) + lane * 4);
        ax = fmaf(v0, __uint_as_float(d0.x << 16),         ax);
        ay = fmaf(v0, __uint_as_float(d0.x & 0xffff0000u), ay);
        az = fmaf(v0, __uint_as_float(d0.y << 16),         az);
        aw = fmaf(v0, __uint_as_float(d0.y & 0xffff0000u), aw);
    }

    const float sc = attn[(size_t)n * 4 + r];
    uint2 st;
    st.x = pack2(sc * ax, sc * ay);
    st.y = pack2(sc * az, sc * aw);
    *reinterpret_cast<uint2*>(agg + ((size_t)wid << 8) + lane * 4) = st;
}

// ---------------------------------------------------------------------------
extern "C" void kernel_launch(void* const* d_in, const int* in_sizes, int n_in,
                              void* d_out, int out_size, void* d_ws, size_t ws_size,
                              hipStream_t stream)
{
    const int*   rows     = (const int*)d_in[0];
    const int*   cols     = (const int*)d_in[1];
    const float* vals     = (const float*)d_in[2];
    const float* node_emb = (const float*)d_in[3];
    const float* pre_W    = (const float*)d_in[4];
    const float* pre_b    = (const float*)d_in[5];
    const float* ln1_g    = (const float*)d_in[6];
    const float* ln1_b    = (const float*)d_in[7];
    const float* rel_W    = (const float*)d_in[8];
    const float* attn_vec = (const float*)d_in[9];
    const float* self_W   = (const float*)d_in[10];
    const float* self_b   = (const float*)d_in[11];
    const float* bias     = (const float*)d_in[12];
    const float* ln2_g    = (const float*)d_in[13];
    const float* ln2_b    = (const float*)d_in[14];

    const int Dd = 256;
    const int R  = in_sizes[8] / (Dd * Dd);   // 4
    const int N  = in_sizes[3] / Dd;          // 50000
    const int E  = in_sizes[0] / R;           // 800000
    const int RE = R * E;                     // 3.2M
    const int RN = R * N;                     // 200000

    const int NB1   = 256;                    // coarse-pass blocks
    const int chunk = (RE + NB1 - 1) / NB1;   // 12500
    const int NBIN  = (RN + 255) / 256;       // 782
    const int NCT   = NBIN * NB1;             // 200192

    float* out  = (float*)d_out;
    float* outF = out;                              // final  [N][256] f32
    float* outA = out + (size_t)N * Dd;             // attn   [N][4]   f32
    float* outX = outA + (size_t)N * R;             // x_all  [N][256] f32

    char* wp = (char*)d_ws;
    auto alloc = [&](size_t bytes) {
        char* p = wp;
        wp += (bytes + 255) & ~(size_t)255;
        return p;
    };
    unsigned short* AGGS = (unsigned short*)alloc((size_t)RN * Dd * 2);   // 102.4 MB
    unsigned short* XB   = (unsigned short*)alloc((size_t)N * Dd * 2);    //  25.6 MB
    unsigned short* EMB  = (unsigned short*)alloc((size_t)N * Dd * 2);    //  25.6 MB
    unsigned short* BTm  = (unsigned short*)alloc((size_t)Dd * 1280 * 2); // 655 KB
    unsigned short* BTp  = (unsigned short*)alloc((size_t)Dd * Dd * 2);   // 131 KB
    float* WT   = (float*)alloc((size_t)R * Dd * 4);
    float* Y    = (float*)alloc((size_t)N * R * 4);
    float* SC   = (float*)alloc((size_t)N * R * 4);
    int* counts = (int*)alloc((size_t)RN * 4);
    int* offs   = (int*)alloc((size_t)RN * 4);
    int* cnt_t  = (int*)alloc((size_t)NCT * 4);     // per-(bin,block) counts
    int* ctoffs = cnt_t;                            // scanned in place
    int* bsums  = (int*)alloc(1024);
    int* bsums2 = (int*)alloc(1024);
    u64* edata  = (u64*)alloc((size_t)RE * 8);      // 25.6 MB (fine)
    u64* edc    = (u64*)alloc((size_t)RE * 8);      // 25.6 MB (coarse)

    const int gblocks = (N + 127) / 128;            // 391
    const int nblkW   = (RN + 1023) / 1024;         // 196
    const int nblkC   = (NCT + 1023) / 1024;        // 196

    // 1. B-matrix prep + emb conversion (+x_all passthrough)
    build_bt<<<(1280 * 256 + 256 * 256 + 255) / 256, 256, 0, stream>>>(
        rel_W, self_W, pre_W, BTm, BTp);
    conv_emb<<<2048, 256, 0, stream>>>(node_emb, EMB, outX, N * Dd / 4);

    // 2. pre-encoder -> X bf16
    gemm_mfma<0><<<gblocks, 512, 0, stream>>>(EMB, nullptr, nullptr, nullptr, nullptr,
                                              BTp, pre_b, nullptr, ln1_g, ln1_b,
                                              nullptr, XB, N);
    // 3. w~ and y
    wtilde_kernel<<<R, 256, 0, stream>>>(rel_W, attn_vec, WT);
    y_kernel<<<(N + 3) / 4, 256, 0, stream>>>(XB, WT, Y, N);

    // 4. CSR build (two-level)
    hipMemsetAsync(counts, 0, (size_t)RN * sizeof(int), stream);
    hist_widbin<<<NB1, 256, 0, stream>>>(rows, counts, cnt_t, RE, E, N, chunk, NBIN);
    // scan per-wid counts -> offs
    scan_blocks<<<nblkW, 256, 0, stream>>>(counts, offs, bsums, RN);
    scan_bsums<<<1, 256, 0, stream>>>(bsums, nblkW);
    scan_add<<<(RN + 255) / 256, 256, 0, stream>>>(offs, bsums, RN);
    // scan per-(bin,block) counts -> ctoffs (in place)
    scan_blocks<<<nblkC, 256, 0, stream>>>(cnt_t, ctoffs, bsums2, NCT);
    scan_bsums<<<1, 256, 0, stream>>>(bsums2, nblkC);
    scan_add<<<(NCT + 255) / 256, 256, 0, stream>>>(ctoffs, bsums2, NCT);
    // coarse then fine scatter
    scatter_coarse<<<NB1, 256, 0, stream>>>(rows, cols, vals, ctoffs, edc,
                                            RE, E, N, chunk, NBIN);
    scatter_fine<<<NBIN, 256, 0, stream>>>(edc, ctoffs, offs, edata, RE, N, NB1, NBIN);

    // 5. edge-wise scores -> masked softmax -> attn (outA)
    score_csr<<<(RN + 255) / 256, 256, 0, stream>>>(offs, edata, Y, SC, N, RE);
    softmax4<<<(N + 255) / 256, 256, 0, stream>>>(SC, outA, N);

    // 6. aggregation with fused attn scaling
    agg_csr<<<(RN + 3) / 4, 256, 0, stream>>>(offs, edata, XB, outA, AGGS, N, RE);

    // 7. mega-GEMM -> final (outF)
    gemm_mfma<1><<<gblocks, 512, 0, stream>>>(AGGS, AGGS + (size_t)N * Dd,
                                              AGGS + (size_t)2 * N * Dd,
                                              AGGS + (size_t)3 * N * Dd, XB,
                                              BTm, bias, self_b, ln2_g, ln2_b,
                                              outF, nullptr, N);
}

// Round 10
// 589.282 us; speedup vs baseline: 1.3933x; 1.1401x over previous
//
#include <hip/hip_runtime.h>
#include <hip/hip_fp16.h>
#include <math.h>

// ---------------------------------------------------------------------------
// LearnableWeightedRGCN — round 10 (R9 + compile fix).
// Changes vs R8:
//  * agg_csr: half-wave 16B gathers (2 edges/wave-instr), packed-f16 hfma2
//    accumulation from an fp16 copy of X, nontemporal edata loads + AGGS
//    stores (keep x L2-resident). Nontemporal store uses ext_vector_type
//    (clang builtin rejects HIP_vector_type uint4 — R9 compile fail).
//  * CSR build: scatter_fine computes per-wid offs itself (bin base + LDS
//    count/scan) -> global per-wid histogram, RN-scan (3 kernels) and counts
//    memset deleted.
//  * pre-GEMM epilogue dual-stores X as bf16 (GEMM/y) and fp16 (gather).
// ---------------------------------------------------------------------------

typedef __attribute__((ext_vector_type(8))) short bf16x8;
typedef __attribute__((ext_vector_type(4))) float f32x4;
typedef __attribute__((ext_vector_type(4))) unsigned u32x4;
typedef unsigned long long u64;

__device__ __forceinline__ float gelu_exact(float v) {
    return 0.5f * v * (1.0f + erff(v * 0.70710678118654752f));
}
__device__ __forceinline__ unsigned short f2bf(float f) {   // RNE
    unsigned u = __float_as_uint(f);
    return (unsigned short)((u + 0x7fffu + ((u >> 16) & 1u)) >> 16);
}
__device__ __forceinline__ unsigned pack2(float a, float b) {
    return (unsigned)f2bf(a) | ((unsigned)f2bf(b) << 16);
}
__device__ __forceinline__ unsigned short f2h(float f) {
    return __half_as_ushort(__float2half(f));
}
__device__ __forceinline__ __half2 u2h2(unsigned u) {
    union { unsigned u; __half2 h; } c; c.u = u; return c.h;
}
__device__ __forceinline__ void gload16(const void* g, void* l) {
    __builtin_amdgcn_global_load_lds(
        (const __attribute__((address_space(1))) void*)g,
        (__attribute__((address_space(3))) void*)l, 16, 0, 0);
}

// ---------------------------------------------------------------------------
// node_emb f32 -> bf16 EMB  +  f32 x_all passthrough (fused copy)
// ---------------------------------------------------------------------------
__global__ __launch_bounds__(256)
void conv_emb(const float* __restrict__ ne, unsigned short* __restrict__ emb,
              float* __restrict__ outX, int total4)
{
    const int stride = gridDim.x * blockDim.x;
    for (int i = blockIdx.x * blockDim.x + threadIdx.x; i < total4; i += stride) {
        const float4 v = reinterpret_cast<const float4*>(ne)[i];
        reinterpret_cast<float4*>(outX)[i] = v;
        ushort4 h;
        h.x = f2bf(v.x); h.y = f2bf(v.y); h.z = f2bf(v.z); h.w = f2bf(v.w);
        reinterpret_cast<ushort4*>(emb)[i] = h;
    }
}

// ---------------------------------------------------------------------------
// B-matrix prep (bf16, transposed)
// ---------------------------------------------------------------------------
__global__ __launch_bounds__(256)
void build_bt(const float* __restrict__ relW, const float* __restrict__ selfW,
              const float* __restrict__ preW, unsigned short* __restrict__ BTm,
              unsigned short* __restrict__ BTp)
{
    const int idx = blockIdx.x * 256 + threadIdx.x;
    if (idx < 1280 * 256) {
        const int k = idx >> 8, n = idx & 255;
        const float v = (k < 1024)
            ? relW[(size_t)(k >> 8) * 65536 + (size_t)(k & 255) * 256 + n]
            : selfW[(size_t)(k - 1024) * 256 + n];
        BTm[(size_t)n * 1280 + k] = f2bf(v);
    } else {
        const int i2 = idx - 1280 * 256;
        if (i2 < 256 * 256) {
            const int k = i2 >> 8, n = i2 & 255;
            BTp[(size_t)n * 256 + k] = f2bf(preW[(size_t)k * 256 + n]);
        }
    }
}

// ---------------------------------------------------------------------------
// MFMA GEMM: BM=128, BN=256, BK=64, 512 threads (8 waves, 2m x 4n).
// MODE 0 additionally stores X as fp16 (XH) for the gather path.
// ---------------------------------------------------------------------------
template<int MODE>
__global__ __launch_bounds__(512)
void gemm_mfma(const unsigned short* __restrict__ a0,
               const unsigned short* __restrict__ a1,
               const unsigned short* __restrict__ a2,
               const unsigned short* __restrict__ a3,
               const unsigned short* __restrict__ a4,
               const unsigned short* __restrict__ BT,
               const float* __restrict__ bias0, const float* __restrict__ bias1,
               const float* __restrict__ lng, const float* __restrict__ lnb,
               float* __restrict__ Cout, unsigned short* __restrict__ XOut,
               unsigned short* __restrict__ XH, int M)
{
    constexpr int K    = MODE ? 1280 : 256;
    constexpr int NSEG = MODE ? 5 : 1;

    __shared__ __align__(16) unsigned char smA[128 * 128];   // 16 KB
    __shared__ __align__(16) unsigned char smB[256 * 128];   // 32 KB
    __shared__ float redS[4][128];
    __shared__ float redQ[4][128];

    const int tid = threadIdx.x;
    const int w   = tid >> 6;
    const int l   = tid & 63;
    const int wm  = w >> 2, wn = w & 3;
    const int brow = blockIdx.x * 128;

    const int srow = l >> 3;
    const int sgA  = (l & 7) ^ srow;

    f32x4 acc[4][4];
#pragma unroll
    for (int mb = 0; mb < 4; ++mb)
#pragma unroll
        for (int nb = 0; nb < 4; ++nb)
            acc[mb][nb] = f32x4{0.f, 0.f, 0.f, 0.f};

    for (int seg = 0; seg < NSEG; ++seg) {
        const unsigned short* Abase =
            (MODE == 0) ? a0
                        : (seg == 0 ? a0 : seg == 1 ? a1 : seg == 2 ? a2
                                         : seg == 3 ? a3 : a4);
#pragma unroll
        for (int kk = 0; kk < 4; ++kk) {
            __syncthreads();
#pragma unroll
            for (int c = 0; c < 2; ++c) {
                const int r0 = (w * 2 + c) * 8;
                int gm = brow + r0 + srow;
                gm = min(gm, M - 1);
                gload16(Abase + ((size_t)gm << 8) + kk * 64 + sgA * 8,
                        smA + (w * 2 + c) * 1024);
            }
#pragma unroll
            for (int c = 0; c < 4; ++c) {
                const int bn = (w * 4 + c) * 8 + srow;
                gload16(BT + (size_t)bn * K + (seg * 4 + kk) * 64 + sgA * 8,
                        smB + (w * 4 + c) * 1024);
            }
            __syncthreads();

#pragma unroll
            for (int ks = 0; ks < 2; ++ks) {
                bf16x8 af[4], bf[4];
#pragma unroll
                for (int mb = 0; mb < 4; ++mb) {
                    const int row = wm * 64 + mb * 16 + (l & 15);
                    const int g   = (ks * 4 + (l >> 4)) ^ (row & 7);
                    af[mb] = *reinterpret_cast<const bf16x8*>(smA + row * 128 + g * 16);
                }
#pragma unroll
                for (int nb = 0; nb < 4; ++nb) {
                    const int row = wn * 64 + nb * 16 + (l & 15);
                    const int g   = (ks * 4 + (l >> 4)) ^ (row & 7);
                    bf[nb] = *reinterpret_cast<const bf16x8*>(smB + row * 128 + g * 16);
                }
#pragma unroll
                for (int mb = 0; mb < 4; ++mb)
#pragma unroll
                    for (int nb = 0; nb < 4; ++nb)
                        acc[mb][nb] = __builtin_amdgcn_mfma_f32_16x16x32_bf16(
                            af[mb], bf[nb], acc[mb][nb], 0, 0, 0);
            }
        }
    }

    // ---- epilogue ----
    float bb[4], gw[4], bw[4];
#pragma unroll
    for (int nb = 0; nb < 4; ++nb) {
        const int n = wn * 64 + nb * 16 + (l & 15);
        bb[nb] = bias0[n] + (MODE == 1 ? bias1[n] : 0.0f);
        gw[nb] = lng[n];
        bw[nb] = lnb[n];
    }
#pragma unroll
    for (int mb = 0; mb < 4; ++mb)
#pragma unroll
        for (int nb = 0; nb < 4; ++nb)
#pragma unroll
            for (int rg = 0; rg < 4; ++rg) {
                float v = acc[mb][nb][rg] + bb[nb];
                if (MODE == 1) v = gelu_exact(v);
                acc[mb][nb][rg] = v;
            }
#pragma unroll
    for (int mb = 0; mb < 4; ++mb)
#pragma unroll
        for (int rg = 0; rg < 4; ++rg) {
            float s = 0.f, q = 0.f;
#pragma unroll
            for (int nb = 0; nb < 4; ++nb) {
                const float v = acc[mb][nb][rg];
                s += v; q += v * v;
            }
#pragma unroll
            for (int off = 1; off < 16; off <<= 1) {
                s += __shfl_xor(s, off, 64);
                q += __shfl_xor(q, off, 64);
            }
            if ((l & 15) == 0) {
                const int row = wm * 64 + mb * 16 + (l >> 4) * 4 + rg;
                redS[wn][row] = s;
                redQ[wn][row] = q;
            }
        }
    __syncthreads();
    if (tid < 128) {
        const float s = redS[0][tid] + redS[1][tid] + redS[2][tid] + redS[3][tid];
        const float q = redQ[0][tid] + redQ[1][tid] + redQ[2][tid] + redQ[3][tid];
        const float mean = s * (1.0f / 256.0f);
        const float var  = q * (1.0f / 256.0f) - mean * mean;
        redS[0][tid] = mean;
        redQ[0][tid] = rsqrtf(var + 1e-5f);
    }
    __syncthreads();
#pragma unroll
    for (int mb = 0; mb < 4; ++mb)
#pragma unroll
        for (int rg = 0; rg < 4; ++rg) {
            const int row = wm * 64 + mb * 16 + (l >> 4) * 4 + rg;
            if (brow + row >= M) continue;
            const float mu = redS[0][row];
            const float rs = redQ[0][row];
#pragma unroll
            for (int nb = 0; nb < 4; ++nb) {
                const int n = wn * 64 + nb * 16 + (l & 15);
                const float v = (acc[mb][nb][rg] - mu) * rs * gw[nb] + bw[nb];
                if (MODE == 0) {
                    const float gv = gelu_exact(v);
                    XOut[((size_t)(brow + row) << 8) + n] = f2bf(gv);
                    XH[((size_t)(brow + row) << 8) + n]   = f2h(gv);
                } else {
                    Cout[((size_t)(brow + row) << 8) + n] = v;
                }
            }
        }
}

// ---------------------------------------------------------------------------
// w~[r][k] = sum_j rel_W[r][k][j] * attn_vec[j]   (fp32)
// ---------------------------------------------------------------------------
__global__ __launch_bounds__(256)
void wtilde_kernel(const float* __restrict__ relW, const float* __restrict__ av,
                   float* __restrict__ wt)
{
    __shared__ float avs[256];
    const int r = blockIdx.x, tid = threadIdx.x;
    avs[tid] = av[tid];
    __syncthreads();
    const float* W = relW + (size_t)r * 65536 + (size_t)tid * 256;
    float s = 0.f;
    for (int j = 0; j < 256; j += 4) {
        const float4 w4 = *reinterpret_cast<const float4*>(W + j);
        s += w4.x * avs[j] + w4.y * avs[j + 1] + w4.z * avs[j + 2] + w4.w * avs[j + 3];
    }
    wt[r * 256 + tid] = s;
}

// ---------------------------------------------------------------------------
// y[n][r] = x[n] . w~[r]  — one wave per node (bf16 X).
// ---------------------------------------------------------------------------
__global__ __launch_bounds__(256)
void y_kernel(const unsigned short* __restrict__ XB, const float* __restrict__ wt,
              float* __restrict__ y, int Nn)
{
    const int n = blockIdx.x * 4 + (threadIdx.x >> 6);
    if (n >= Nn) return;
    const int l = threadIdx.x & 63;
    const uint2 d = *reinterpret_cast<const uint2*>(XB + ((size_t)n << 8) + l * 4);
    float xv[4];
    xv[0] = __uint_as_float(d.x << 16);
    xv[1] = __uint_as_float(d.x & 0xffff0000u);
    xv[2] = __uint_as_float(d.y << 16);
    xv[3] = __uint_as_float(d.y & 0xffff0000u);
    float s[4];
#pragma unroll
    for (int r = 0; r < 4; ++r) {
        const float4 w4 = *reinterpret_cast<const float4*>(wt + r * 256 + l * 4);
        s[r] = xv[0] * w4.x + xv[1] * w4.y + xv[2] * w4.z + xv[3] * w4.w;
#pragma unroll
        for (int off = 32; off; off >>= 1) s[r] += __shfl_xor(s[r], off, 64);
    }
    if (l == 0)
        *reinterpret_cast<float4*>(y + (size_t)n * 4) = make_float4(s[0], s[1], s[2], s[3]);
}

// ---------------------------------------------------------------------------
// Bin histogram only (per-(block,bin) counts for the coarse scatter).
// ---------------------------------------------------------------------------
__global__ __launch_bounds__(256)
void hist_bin(const int* __restrict__ rows, int* __restrict__ cnt_t,
              int RE, int E, int Nn, int chunk, int NBIN)
{
    __shared__ int lh[800];
    const int blk = blockIdx.x;
    for (int i = threadIdx.x; i < NBIN; i += 256) lh[i] = 0;
    __syncthreads();
    const int e0 = blk * chunk;
    const int e1 = min(e0 + chunk, RE);
    for (int e = e0 + threadIdx.x; e < e1; e += 256) {
        const int r   = e / E;
        const int wid = r * Nn + rows[e];
        atomicAdd(&lh[wid >> 8], 1);
    }
    __syncthreads();
    for (int i = threadIdx.x; i < NBIN; i += 256)
        cnt_t[i * gridDim.x + blk] = lh[i];
}

// ---------------------------------------------------------------------------
// Exclusive scan (generic)
// ---------------------------------------------------------------------------
__global__ __launch_bounds__(256)
void scan_blocks(const int* __restrict__ counts, int* __restrict__ offs,
                 int* __restrict__ bsums, int n)
{
    __shared__ int sh[256];
    const int t = threadIdx.x;
    const int base = blockIdx.x * 1024 + t * 4;
    int v[4], s = 0;
#pragma unroll
    for (int j = 0; j < 4; ++j) {
        v[j] = (base + j < n) ? counts[base + j] : 0;
        s += v[j];
    }
    sh[t] = s;
    __syncthreads();
    for (int off = 1; off < 256; off <<= 1) {
        const int x = (t >= off) ? sh[t - off] : 0;
        __syncthreads();
        sh[t] += x;
        __syncthreads();
    }
    int run = sh[t] - s;
    if (t == 255) bsums[blockIdx.x] = sh[255];
#pragma unroll
    for (int j = 0; j < 4; ++j) {
        if (base + j < n) offs[base + j] = run;
        run += v[j];
    }
}

__global__ __launch_bounds__(256)
void scan_bsums(int* __restrict__ bsums, int nblk)
{
    __shared__ int sh[256];
    const int t = threadIdx.x;
    const int v = (t < nblk) ? bsums[t] : 0;
    sh[t] = v;
    __syncthreads();
    for (int off = 1; off < 256; off <<= 1) {
        const int x = (t >= off) ? sh[t - off] : 0;
        __syncthreads();
        sh[t] += x;
        __syncthreads();
    }
    if (t < nblk) bsums[t] = sh[t] - v;
}

__global__ __launch_bounds__(256)
void scan_add(int* __restrict__ offs, const int* __restrict__ bsums, int n)
{
    const int i = blockIdx.x * 256 + threadIdx.x;
    if (i >= n) return;
    offs[i] += bsums[i >> 10];
}

// ---------------------------------------------------------------------------
// Coarse scatter: edges -> block-private per-bin regions (LDS cursors).
// Payload: (val[31:2]|r) << 32 | row<<16 | col.
// ---------------------------------------------------------------------------
__global__ __launch_bounds__(256)
void scatter_coarse(const int* __restrict__ rows, const int* __restrict__ cols,
                    const float* __restrict__ vals, const int* __restrict__ ctoffs,
                    u64* __restrict__ edc, int RE, int E, int Nn,
                    int chunk, int NBIN)
{
    __shared__ int lcur[800];
    const int blk = blockIdx.x;
    for (int i = threadIdx.x; i < NBIN; i += 256)
        lcur[i] = ctoffs[i * gridDim.x + blk];
    __syncthreads();
    const int e0 = blk * chunk;
    const int e1 = min(e0 + chunk, RE);
    for (int e = e0 + threadIdx.x; e < e1; e += 256) {
        const int r   = e / E;
        const int row = rows[e];
        const int wid = r * Nn + row;
        const int pos = atomicAdd(&lcur[wid >> 8], 1);
        const unsigned vb = __float_as_uint(vals[e]);
        edc[pos] = ((u64)((vb & 0xFFFFFFFCu) | (unsigned)r) << 32)
                 | ((unsigned)row << 16) | (unsigned)cols[e];
    }
}

// ---------------------------------------------------------------------------
// Fine scatter: one block per bin (256 wids). Pass 1 counts per-wid in LDS,
// LDS scan -> offs[wid] = bin_start + prefix (writes global offs). Pass 2
// re-reads the (L2-resident) segment and places edges.
// ---------------------------------------------------------------------------
__global__ __launch_bounds__(256)
void scatter_fine(const u64* __restrict__ edc, const int* __restrict__ ctoffs,
                  int* __restrict__ offs, u64* __restrict__ edata,
                  int RE, int Nn, int NB1, int NBIN)
{
    __shared__ int cnt[256];
    __shared__ int cur[256];
    const int bin     = blockIdx.x;
    const int widbase = bin << 8;
    const int RN      = Nn << 2;
    const int t       = threadIdx.x;
    cnt[t] = 0;
    __syncthreads();
    const int cs = ctoffs[bin * NB1];
    const int ce = (bin + 1 < NBIN) ? ctoffs[(bin + 1) * NB1] : RE;
    // pass 1: per-wid counts
    for (int j = cs + t; j < ce; j += 256) {
        const u64 p = edc[j];
        const unsigned hi = (unsigned)(p >> 32);
        const unsigned lo = (unsigned)p;
        const int w = (int)(hi & 3u) * Nn + (int)(lo >> 16);
        atomicAdd(&cnt[w - widbase], 1);
    }
    __syncthreads();
    // LDS exclusive scan of 256 counts
    const int v = cnt[t];
    cur[t] = v;
    __syncthreads();
    for (int off = 1; off < 256; off <<= 1) {
        const int x = (t >= off) ? cur[t - off] : 0;
        __syncthreads();
        cur[t] += x;
        __syncthreads();
    }
    const int excl = cur[t] - v;
    const int wid  = widbase + t;
    if (wid < RN) offs[wid] = cs + excl;
    __syncthreads();
    cur[t] = cs + excl;
    __syncthreads();
    // pass 2: place
    for (int j = cs + t; j < ce; j += 256) {
        const u64 p  = edc[j];
        const unsigned hi = (unsigned)(p >> 32);
        const unsigned lo = (unsigned)p;
        const int w   = (int)(hi & 3u) * Nn + (int)(lo >> 16);
        const int pos = atomicAdd(&cur[w - widbase], 1);
        edata[pos] = ((u64)(hi & 0xFFFFFFFCu) << 32) | (lo & 0xFFFFu);
    }
}

// ---------------------------------------------------------------------------
// Edge-wise scores: score[n][r] = sum val * y[col][r]; sentinel if deg==0.
// ---------------------------------------------------------------------------
__global__ __launch_bounds__(256)
void score_csr(const int* __restrict__ offs, const u64* __restrict__ edata,
               const float* __restrict__ y, float* __restrict__ scores,
               int Nn, int RE)
{
    const int wid = blockIdx.x * 256 + threadIdx.x;
    const int RN  = Nn << 2;
    if (wid >= RN) return;
    const int r = wid / Nn;
    const int n = wid - r * Nn;
    const int start = offs[wid];
    const int end   = (wid + 1 < RN) ? offs[wid + 1] : RE;

    float s = 0.f;
    int j = start;
    for (; j + 3 < end; j += 4) {
        u64 e[4];
        float yv[4], vv[4];
#pragma unroll
        for (int q = 0; q < 4; ++q) e[q] = __builtin_nontemporal_load(edata + j + q);
#pragma unroll
        for (int q = 0; q < 4; ++q) {
            vv[q] = __uint_as_float((unsigned)(e[q] >> 32));
            yv[q] = y[((size_t)(unsigned)(e[q] & 0xffffffffu)) * 4 + r];
        }
#pragma unroll
        for (int q = 0; q < 4; ++q) s = fmaf(vv[q], yv[q], s);
    }
    for (; j < end; ++j) {
        const u64 e0 = edata[j];
        s = fmaf(__uint_as_float((unsigned)(e0 >> 32)),
                 y[((size_t)(unsigned)(e0 & 0xffffffffu)) * 4 + r], s);
    }
    scores[(size_t)n * 4 + r] = (end > start) ? s : -1e30f;
}

// ---------------------------------------------------------------------------
// Per-node masked softmax over 4 relation scores.
// ---------------------------------------------------------------------------
__global__ __launch_bounds__(256)
void softmax4(const float* __restrict__ scores, float* __restrict__ attn, int Nn)
{
    const int n = blockIdx.x * 256 + threadIdx.x;
    if (n >= Nn) return;
    const float4 s4 = *reinterpret_cast<const float4*>(scores + (size_t)n * 4);
    float s[4] = { s4.x, s4.y, s4.z, s4.w };
    float mx = -3.0e38f;
#pragma unroll
    for (int r = 0; r < 4; ++r) mx = fmaxf(mx, s[r]);
    float ex[4], es = 0.f;
#pragma unroll
    for (int r = 0; r < 4; ++r) { ex[r] = expf(s[r] - mx); es += ex[r]; }
    const float inv = 1.0f / es;
    float4 o;
    o.x = (s[0] > -1e29f) ? ex[0] * inv : 0.0f;
    o.y = (s[1] > -1e29f) ? ex[1] * inv : 0.0f;
    o.z = (s[2] > -1e29f) ? ex[2] * inv : 0.0f;
    o.w = (s[3] > -1e29f) ? ex[3] * inv : 0.0f;
    *reinterpret_cast<float4*>(attn + (size_t)n * 4) = o;
}

// ---------------------------------------------------------------------------
// Aggregation: one wave per (r,n); half-waves process alternating edges with
// 16B f16 gathers + packed hfma2; halves combined via shfl_xor(32). Scaled
// bf16 store (nontemporal, ext_vector). edata loads nontemporal.
// ---------------------------------------------------------------------------
__global__ __launch_bounds__(256)
void agg_csr(const int* __restrict__ offs, const u64* __restrict__ edata,
             const unsigned short* __restrict__ xh, const float* __restrict__ attn,
             unsigned short* __restrict__ agg, int Nn, int RE)
{
    const int wid  = (blockIdx.x << 2) + (threadIdx.x >> 6);
    const int lane = threadIdx.x & 63;
    const int half = lane >> 5;
    const int sub  = lane & 31;
    const int RN   = Nn << 2;
    if (wid >= RN) return;
    const int r = wid / Nn;
    const int n = wid - r * Nn;

    const int start = offs[wid];
    const int end   = (wid + 1 < RN) ? offs[wid + 1] : RE;

    __half2 acc0 = __float2half2_rn(0.f), acc1 = acc0, acc2 = acc0, acc3 = acc0;

    int j = start + half;
    for (; j + 2 < end; j += 4) {
        const u64 e0 = __builtin_nontemporal_load(edata + j);
        const u64 e1 = __builtin_nontemporal_load(edata + j + 2);
        const int c0 = (int)(e0 & 0xffffffffu);
        const int c1 = (int)(e1 & 0xffffffffu);
        const __half2 v0 = __float2half2_rn(__uint_as_float((unsigned)(e0 >> 32)));
        const __half2 v1 = __float2half2_rn(__uint_as_float((unsigned)(e1 >> 32)));
        const uint4 d0 = *reinterpret_cast<const uint4*>(xh + ((size_t)c0 << 8) + sub * 8);
        const uint4 d1 = *reinterpret_cast<const uint4*>(xh + ((size_t)c1 << 8) + sub * 8);
        acc0 = __hfma2(v0, u2h2(d0.x), acc0);
        acc1 = __hfma2(v0, u2h2(d0.y), acc1);
        acc2 = __hfma2(v0, u2h2(d0.z), acc2);
        acc3 = __hfma2(v0, u2h2(d0.w), acc3);
        acc0 = __hfma2(v1, u2h2(d1.x), acc0);
        acc1 = __hfma2(v1, u2h2(d1.y), acc1);
        acc2 = __hfma2(v1, u2h2(d1.z), acc2);
        acc3 = __hfma2(v1, u2h2(d1.w), acc3);
    }
    for (; j < end; j += 2) {
        const u64 e0 = __builtin_nontemporal_load(edata + j);
        const int c0 = (int)(e0 & 0xffffffffu);
        const __half2 v0 = __float2half2_rn(__uint_as_float((unsigned)(e0 >> 32)));
        const uint4 d0 = *reinterpret_cast<const uint4*>(xh + ((size_t)c0 << 8) + sub * 8);
        acc0 = __hfma2(v0, u2h2(d0.x), acc0);
        acc1 = __hfma2(v0, u2h2(d0.y), acc1);
        acc2 = __hfma2(v0, u2h2(d0.z), acc2);
        acc3 = __hfma2(v0, u2h2(d0.w), acc3);
    }

    float a[8];
    a[0] = __low2float(acc0); a[1] = __high2float(acc0);
    a[2] = __low2float(acc1); a[3] = __high2float(acc1);
    a[4] = __low2float(acc2); a[5] = __high2float(acc2);
    a[6] = __low2float(acc3); a[7] = __high2float(acc3);
#pragma unroll
    for (int i = 0; i < 8; ++i) a[i] += __shfl_xor(a[i], 32, 64);

    if (half == 0) {
        const float sc = attn[(size_t)n * 4 + r];
        u32x4 st;
        st.x = pack2(sc * a[0], sc * a[1]);
        st.y = pack2(sc * a[2], sc * a[3]);
        st.z = pack2(sc * a[4], sc * a[5]);
        st.w = pack2(sc * a[6], sc * a[7]);
        __builtin_nontemporal_store(
            st, reinterpret_cast<u32x4*>(agg + ((size_t)wid << 8) + sub * 8));
    }
}

// ---------------------------------------------------------------------------
extern "C" void kernel_launch(void* const* d_in, const int* in_sizes, int n_in,
                              void* d_out, int out_size, void* d_ws, size_t ws_size,
                              hipStream_t stream)
{
    const int*   rows     = (const int*)d_in[0];
    const int*   cols     = (const int*)d_in[1];
    const float* vals     = (const float*)d_in[2];
    const float* node_emb = (const float*)d_in[3];
    const float* pre_W    = (const float*)d_in[4];
    const float* pre_b    = (const float*)d_in[5];
    const float* ln1_g    = (const float*)d_in[6];
    const float* ln1_b    = (const float*)d_in[7];
    const float* rel_W    = (const float*)d_in[8];
    const float* attn_vec = (const float*)d_in[9];
    const float* self_W   = (const float*)d_in[10];
    const float* self_b   = (const float*)d_in[11];
    const float* bias     = (const float*)d_in[12];
    const float* ln2_g    = (const float*)d_in[13];
    const float* ln2_b    = (const float*)d_in[14];

    const int Dd = 256;
    const int R  = in_sizes[8] / (Dd * Dd);   // 4
    const int N  = in_sizes[3] / Dd;          // 50000
    const int E  = in_sizes[0] / R;           // 800000
    const int RE = R * E;                     // 3.2M
    const int RN = R * N;                     // 200000

    const int NB1   = 256;
    const int chunk = (RE + NB1 - 1) / NB1;   // 12500
    const int NBIN  = (RN + 255) / 256;       // 782
    const int NCT   = NBIN * NB1;             // 200192

    float* out  = (float*)d_out;
    float* outF = out;                              // final  [N][256] f32
    float* outA = out + (size_t)N * Dd;             // attn   [N][4]   f32
    float* outX = outA + (size_t)N * R;             // x_all  [N][256] f32

    char* wp = (char*)d_ws;
    auto alloc = [&](size_t bytes) {
        char* p = wp;
        wp += (bytes + 255) & ~(size_t)255;
        return p;
    };
    unsigned short* AGGS = (unsigned short*)alloc((size_t)RN * Dd * 2);   // 102.4 MB
    unsigned short* XB   = (unsigned short*)alloc((size_t)N * Dd * 2);    //  25.6 MB
    unsigned short* XH   = (unsigned short*)alloc((size_t)N * Dd * 2);    //  25.6 MB
    unsigned short* EMB  = (unsigned short*)alloc((size_t)N * Dd * 2);    //  25.6 MB
    unsigned short* BTm  = (unsigned short*)alloc((size_t)Dd * 1280 * 2); // 655 KB
    unsigned short* BTp  = (unsigned short*)alloc((size_t)Dd * Dd * 2);   // 131 KB
    float* WT   = (float*)alloc((size_t)R * Dd * 4);
    float* Y    = (float*)alloc((size_t)N * R * 4);
    float* SC   = (float*)alloc((size_t)N * R * 4);
    int* offs   = (int*)alloc((size_t)RN * 4);
    int* cnt_t  = (int*)alloc((size_t)NCT * 4);
    int* ctoffs = cnt_t;                            // scanned in place
    int* bsums2 = (int*)alloc(1024);
    u64* edata  = (u64*)alloc((size_t)RE * 8);      // 25.6 MB (fine)
    u64* edc    = (u64*)alloc((size_t)RE * 8);      // 25.6 MB (coarse)

    const int gblocks = (N + 127) / 128;            // 391
    const int nblkC   = (NCT + 1023) / 1024;        // 196

    // 1. B-matrix prep + emb conversion (+x_all passthrough)
    build_bt<<<(1280 * 256 + 256 * 256 + 255) / 256, 256, 0, stream>>>(
        rel_W, self_W, pre_W, BTm, BTp);
    conv_emb<<<2048, 256, 0, stream>>>(node_emb, EMB, outX, N * Dd / 4);

    // 2. pre-encoder -> X (bf16 + f16 copies)
    gemm_mfma<0><<<gblocks, 512, 0, stream>>>(EMB, nullptr, nullptr, nullptr, nullptr,
                                              BTp, pre_b, nullptr, ln1_g, ln1_b,
                                              nullptr, XB, XH, N);
    // 3. w~ and y
    wtilde_kernel<<<R, 256, 0, stream>>>(rel_W, attn_vec, WT);
    y_kernel<<<(N + 3) / 4, 256, 0, stream>>>(XB, WT, Y, N);

    // 4. CSR build (two-level; offs derived in fine pass)
    hist_bin<<<NB1, 256, 0, stream>>>(rows, cnt_t, RE, E, N, chunk, NBIN);
    scan_blocks<<<nblkC, 256, 0, stream>>>(cnt_t, ctoffs, bsums2, NCT);
    scan_bsums<<<1, 256, 0, stream>>>(bsums2, nblkC);
    scan_add<<<(NCT + 255) / 256, 256, 0, stream>>>(ctoffs, bsums2, NCT);
    scatter_coarse<<<NB1, 256, 0, stream>>>(rows, cols, vals, ctoffs, edc,
                                            RE, E, N, chunk, NBIN);
    scatter_fine<<<NBIN, 256, 0, stream>>>(edc, ctoffs, offs, edata, RE, N, NB1, NBIN);

    // 5. edge-wise scores -> masked softmax -> attn (outA)
    score_csr<<<(RN + 255) / 256, 256, 0, stream>>>(offs, edata, Y, SC, N, RE);
    softmax4<<<(N + 255) / 256, 256, 0, stream>>>(SC, outA, N);

    // 6. aggregation with fused attn scaling (f16 gather, packed fma)
    agg_csr<<<(RN + 3) / 4, 256, 0, stream>>>(offs, edata, XH, outA, AGGS, N, RE);

    // 7. mega-GEMM -> final (outF)
    gemm_mfma<1><<<gblocks, 512, 0, stream>>>(AGGS, AGGS + (size_t)N * Dd,
                                              AGGS + (size_t)2 * N * Dd,
                                              AGGS + (size_t)3 * N * Dd, XB,
                                              BTm, bias, self_b, ln2_g, ln2_b,
                                              outF, nullptr, nullptr, N);
}

// Round 11
// 560.050 us; speedup vs baseline: 1.4660x; 1.0522x over previous
//
#include <hip/hip_runtime.h>
#include <hip/hip_fp16.h>
#include <math.h>

// ---------------------------------------------------------------------------
// LearnableWeightedRGCN — round 11.
// Changes vs R10:
//  * agg_csr: 4-deep gather pipeline per half-wave (8 edges in flight per
//    wave iteration) — MLP test against the L3-path ceiling.
//  * score fused into scatter_fine pass 2 (y-gather + LDS score accum);
//    score_csr kernel deleted (-25.6 MB edata re-read, -1 launch).
// ---------------------------------------------------------------------------

typedef __attribute__((ext_vector_type(8))) short bf16x8;
typedef __attribute__((ext_vector_type(4))) float f32x4;
typedef __attribute__((ext_vector_type(4))) unsigned u32x4;
typedef unsigned long long u64;

__device__ __forceinline__ float gelu_exact(float v) {
    return 0.5f * v * (1.0f + erff(v * 0.70710678118654752f));
}
__device__ __forceinline__ unsigned short f2bf(float f) {   // RNE
    unsigned u = __float_as_uint(f);
    return (unsigned short)((u + 0x7fffu + ((u >> 16) & 1u)) >> 16);
}
__device__ __forceinline__ unsigned pack2(float a, float b) {
    return (unsigned)f2bf(a) | ((unsigned)f2bf(b) << 16);
}
__device__ __forceinline__ unsigned short f2h(float f) {
    return __half_as_ushort(__float2half(f));
}
__device__ __forceinline__ __half2 u2h2(unsigned u) {
    union { unsigned u; __half2 h; } c; c.u = u; return c.h;
}
__device__ __forceinline__ void gload16(const void* g, void* l) {
    __builtin_amdgcn_global_load_lds(
        (const __attribute__((address_space(1))) void*)g,
        (__attribute__((address_space(3))) void*)l, 16, 0, 0);
}

// ---------------------------------------------------------------------------
// node_emb f32 -> bf16 EMB  +  f32 x_all passthrough (fused copy)
// ---------------------------------------------------------------------------
__global__ __launch_bounds__(256)
void conv_emb(const float* __restrict__ ne, unsigned short* __restrict__ emb,
              float* __restrict__ outX, int total4)
{
    const int stride = gridDim.x * blockDim.x;
    for (int i = blockIdx.x * blockDim.x + threadIdx.x; i < total4; i += stride) {
        const float4 v = reinterpret_cast<const float4*>(ne)[i];
        reinterpret_cast<float4*>(outX)[i] = v;
        ushort4 h;
        h.x = f2bf(v.x); h.y = f2bf(v.y); h.z = f2bf(v.z); h.w = f2bf(v.w);
        reinterpret_cast<ushort4*>(emb)[i] = h;
    }
}

// ---------------------------------------------------------------------------
// B-matrix prep (bf16, transposed)
// ---------------------------------------------------------------------------
__global__ __launch_bounds__(256)
void build_bt(const float* __restrict__ relW, const float* __restrict__ selfW,
              const float* __restrict__ preW, unsigned short* __restrict__ BTm,
              unsigned short* __restrict__ BTp)
{
    const int idx = blockIdx.x * 256 + threadIdx.x;
    if (idx < 1280 * 256) {
        const int k = idx >> 8, n = idx & 255;
        const float v = (k < 1024)
            ? relW[(size_t)(k >> 8) * 65536 + (size_t)(k & 255) * 256 + n]
            : selfW[(size_t)(k - 1024) * 256 + n];
        BTm[(size_t)n * 1280 + k] = f2bf(v);
    } else {
        const int i2 = idx - 1280 * 256;
        if (i2 < 256 * 256) {
            const int k = i2 >> 8, n = i2 & 255;
            BTp[(size_t)n * 256 + k] = f2bf(preW[(size_t)k * 256 + n]);
        }
    }
}

// ---------------------------------------------------------------------------
// MFMA GEMM: BM=128, BN=256, BK=64, 512 threads (8 waves, 2m x 4n).
// MODE 0 additionally stores X as fp16 (XH) for the gather path.
// ---------------------------------------------------------------------------
template<int MODE>
__global__ __launch_bounds__(512)
void gemm_mfma(const unsigned short* __restrict__ a0,
               const unsigned short* __restrict__ a1,
               const unsigned short* __restrict__ a2,
               const unsigned short* __restrict__ a3,
               const unsigned short* __restrict__ a4,
               const unsigned short* __restrict__ BT,
               const float* __restrict__ bias0, const float* __restrict__ bias1,
               const float* __restrict__ lng, const float* __restrict__ lnb,
               float* __restrict__ Cout, unsigned short* __restrict__ XOut,
               unsigned short* __restrict__ XH, int M)
{
    constexpr int K    = MODE ? 1280 : 256;
    constexpr int NSEG = MODE ? 5 : 1;

    __shared__ __align__(16) unsigned char smA[128 * 128];   // 16 KB
    __shared__ __align__(16) unsigned char smB[256 * 128];   // 32 KB
    __shared__ float redS[4][128];
    __shared__ float redQ[4][128];

    const int tid = threadIdx.x;
    const int w   = tid >> 6;
    const int l   = tid & 63;
    const int wm  = w >> 2, wn = w & 3;
    const int brow = blockIdx.x * 128;

    const int srow = l >> 3;
    const int sgA  = (l & 7) ^ srow;

    f32x4 acc[4][4];
#pragma unroll
    for (int mb = 0; mb < 4; ++mb)
#pragma unroll
        for (int nb = 0; nb < 4; ++nb)
            acc[mb][nb] = f32x4{0.f, 0.f, 0.f, 0.f};

    for (int seg = 0; seg < NSEG; ++seg) {
        const unsigned short* Abase =
            (MODE == 0) ? a0
                        : (seg == 0 ? a0 : seg == 1 ? a1 : seg == 2 ? a2
                                         : seg == 3 ? a3 : a4);
#pragma unroll
        for (int kk = 0; kk < 4; ++kk) {
            __syncthreads();
#pragma unroll
            for (int c = 0; c < 2; ++c) {
                const int r0 = (w * 2 + c) * 8;
                int gm = brow + r0 + srow;
                gm = min(gm, M - 1);
                gload16(Abase + ((size_t)gm << 8) + kk * 64 + sgA * 8,
                        smA + (w * 2 + c) * 1024);
            }
#pragma unroll
            for (int c = 0; c < 4; ++c) {
                const int bn = (w * 4 + c) * 8 + srow;
                gload16(BT + (size_t)bn * K + (seg * 4 + kk) * 64 + sgA * 8,
                        smB + (w * 4 + c) * 1024);
            }
            __syncthreads();

#pragma unroll
            for (int ks = 0; ks < 2; ++ks) {
                bf16x8 af[4], bf[4];
#pragma unroll
                for (int mb = 0; mb < 4; ++mb) {
                    const int row = wm * 64 + mb * 16 + (l & 15);
                    const int g   = (ks * 4 + (l >> 4)) ^ (row & 7);
                    af[mb] = *reinterpret_cast<const bf16x8*>(smA + row * 128 + g * 16);
                }
#pragma unroll
                for (int nb = 0; nb < 4; ++nb) {
                    const int row = wn * 64 + nb * 16 + (l & 15);
                    const int g   = (ks * 4 + (l >> 4)) ^ (row & 7);
                    bf[nb] = *reinterpret_cast<const bf16x8*>(smB + row * 128 + g * 16);
                }
#pragma unroll
                for (int mb = 0; mb < 4; ++mb)
#pragma unroll
                    for (int nb = 0; nb < 4; ++nb)
                        acc[mb][nb] = __builtin_amdgcn_mfma_f32_16x16x32_bf16(
                            af[mb], bf[nb], acc[mb][nb], 0, 0, 0);
            }
        }
    }

    // ---- epilogue ----
    float bb[4], gw[4], bw[4];
#pragma unroll
    for (int nb = 0; nb < 4; ++nb) {
        const int n = wn * 64 + nb * 16 + (l & 15);
        bb[nb] = bias0[n] + (MODE == 1 ? bias1[n] : 0.0f);
        gw[nb] = lng[n];
        bw[nb] = lnb[n];
    }
#pragma unroll
    for (int mb = 0; mb < 4; ++mb)
#pragma unroll
        for (int nb = 0; nb < 4; ++nb)
#pragma unroll
            for (int rg = 0; rg < 4; ++rg) {
                float v = acc[mb][nb][rg] + bb[nb];
                if (MODE == 1) v = gelu_exact(v);
                acc[mb][nb][rg] = v;
            }
#pragma unroll
    for (int mb = 0; mb < 4; ++mb)
#pragma unroll
        for (int rg = 0; rg < 4; ++rg) {
            float s = 0.f, q = 0.f;
#pragma unroll
            for (int nb = 0; nb < 4; ++nb) {
                const float v = acc[mb][nb][rg];
                s += v; q += v * v;
            }
#pragma unroll
            for (int off = 1; off < 16; off <<= 1) {
                s += __shfl_xor(s, off, 64);
                q += __shfl_xor(q, off, 64);
            }
            if ((l & 15) == 0) {
                const int row = wm * 64 + mb * 16 + (l >> 4) * 4 + rg;
                redS[wn][row] = s;
                redQ[wn][row] = q;
            }
        }
    __syncthreads();
    if (tid < 128) {
        const float s = redS[0][tid] + redS[1][tid] + redS[2][tid] + redS[3][tid];
        const float q = redQ[0][tid] + redQ[1][tid] + redQ[2][tid] + redQ[3][tid];
        const float mean = s * (1.0f / 256.0f);
        const float var  = q * (1.0f / 256.0f) - mean * mean;
        redS[0][tid] = mean;
        redQ[0][tid] = rsqrtf(var + 1e-5f);
    }
    __syncthreads();
#pragma unroll
    for (int mb = 0; mb < 4; ++mb)
#pragma unroll
        for (int rg = 0; rg < 4; ++rg) {
            const int row = wm * 64 + mb * 16 + (l >> 4) * 4 + rg;
            if (brow + row >= M) continue;
            const float mu = redS[0][row];
            const float rs = redQ[0][row];
#pragma unroll
            for (int nb = 0; nb < 4; ++nb) {
                const int n = wn * 64 + nb * 16 + (l & 15);
                const float v = (acc[mb][nb][rg] - mu) * rs * gw[nb] + bw[nb];
                if (MODE == 0) {
                    const float gv = gelu_exact(v);
                    XOut[((size_t)(brow + row) << 8) + n] = f2bf(gv);
                    XH[((size_t)(brow + row) << 8) + n]   = f2h(gv);
                } else {
                    Cout[((size_t)(brow + row) << 8) + n] = v;
                }
            }
        }
}

// ---------------------------------------------------------------------------
// w~[r][k] = sum_j rel_W[r][k][j] * attn_vec[j]   (fp32)
// ---------------------------------------------------------------------------
__global__ __launch_bounds__(256)
void wtilde_kernel(const float* __restrict__ relW, const float* __restrict__ av,
                   float* __restrict__ wt)
{
    __shared__ float avs[256];
    const int r = blockIdx.x, tid = threadIdx.x;
    avs[tid] = av[tid];
    __syncthreads();
    const float* W = relW + (size_t)r * 65536 + (size_t)tid * 256;
    float s = 0.f;
    for (int j = 0; j < 256; j += 4) {
        const float4 w4 = *reinterpret_cast<const float4*>(W + j);
        s += w4.x * avs[j] + w4.y * avs[j + 1] + w4.z * avs[j + 2] + w4.w * avs[j + 3];
    }
    wt[r * 256 + tid] = s;
}

// ---------------------------------------------------------------------------
// y[n][r] = x[n] . w~[r]  — one wave per node (bf16 X).
// ---------------------------------------------------------------------------
__global__ __launch_bounds__(256)
void y_kernel(const unsigned short* __restrict__ XB, const float* __restrict__ wt,
              float* __restrict__ y, int Nn)
{
    const int n = blockIdx.x * 4 + (threadIdx.x >> 6);
    if (n >= Nn) return;
    const int l = threadIdx.x & 63;
    const uint2 d = *reinterpret_cast<const uint2*>(XB + ((size_t)n << 8) + l * 4);
    float xv[4];
    xv[0] = __uint_as_float(d.x << 16);
    xv[1] = __uint_as_float(d.x & 0xffff0000u);
    xv[2] = __uint_as_float(d.y << 16);
    xv[3] = __uint_as_float(d.y & 0xffff0000u);
    float s[4];
#pragma unroll
    for (int r = 0; r < 4; ++r) {
        const float4 w4 = *reinterpret_cast<const float4*>(wt + r * 256 + l * 4);
        s[r] = xv[0] * w4.x + xv[1] * w4.y + xv[2] * w4.z + xv[3] * w4.w;
#pragma unroll
        for (int off = 32; off; off >>= 1) s[r] += __shfl_xor(s[r], off, 64);
    }
    if (l == 0)
        *reinterpret_cast<float4*>(y + (size_t)n * 4) = make_float4(s[0], s[1], s[2], s[3]);
}

// ---------------------------------------------------------------------------
// Bin histogram (per-(block,bin) counts for the coarse scatter).
// ---------------------------------------------------------------------------
__global__ __launch_bounds__(256)
void hist_bin(const int* __restrict__ rows, int* __restrict__ cnt_t,
              int RE, int E, int Nn, int chunk, int NBIN)
{
    __shared__ int lh[800];
    const int blk = blockIdx.x;
    for (int i = threadIdx.x; i < NBIN; i += 256) lh[i] = 0;
    __syncthreads();
    const int e0 = blk * chunk;
    const int e1 = min(e0 + chunk, RE);
    for (int e = e0 + threadIdx.x; e < e1; e += 256) {
        const int r   = e / E;
        const int wid = r * Nn + rows[e];
        atomicAdd(&lh[wid >> 8], 1);
    }
    __syncthreads();
    for (int i = threadIdx.x; i < NBIN; i += 256)
        cnt_t[i * gridDim.x + blk] = lh[i];
}

// ---------------------------------------------------------------------------
// Exclusive scan (generic)
// ---------------------------------------------------------------------------
__global__ __launch_bounds__(256)
void scan_blocks(const int* __restrict__ counts, int* __restrict__ offs,
                 int* __restrict__ bsums, int n)
{
    __shared__ int sh[256];
    const int t = threadIdx.x;
    const int base = blockIdx.x * 1024 + t * 4;
    int v[4], s = 0;
#pragma unroll
    for (int j = 0; j < 4; ++j) {
        v[j] = (base + j < n) ? counts[base + j] : 0;
        s += v[j];
    }
    sh[t] = s;
    __syncthreads();
    for (int off = 1; off < 256; off <<= 1) {
        const int x = (t >= off) ? sh[t - off] : 0;
        __syncthreads();
        sh[t] += x;
        __syncthreads();
    }
    int run = sh[t] - s;
    if (t == 255) bsums[blockIdx.x] = sh[255];
#pragma unroll
    for (int j = 0; j < 4; ++j) {
        if (base + j < n) offs[base + j] = run;
        run += v[j];
    }
}

__global__ __launch_bounds__(256)
void scan_bsums(int* __restrict__ bsums, int nblk)
{
    __shared__ int sh[256];
    const int t = threadIdx.x;
    const int v = (t < nblk) ? bsums[t] : 0;
    sh[t] = v;
    __syncthreads();
    for (int off = 1; off < 256; off <<= 1) {
        const int x = (t >= off) ? sh[t - off] : 0;
        __syncthreads();
        sh[t] += x;
        __syncthreads();
    }
    if (t < nblk) bsums[t] = sh[t] - v;
}

__global__ __launch_bounds__(256)
void scan_add(int* __restrict__ offs, const int* __restrict__ bsums, int n)
{
    const int i = blockIdx.x * 256 + threadIdx.x;
    if (i >= n) return;
    offs[i] += bsums[i >> 10];
}

// ---------------------------------------------------------------------------
// Coarse scatter: edges -> block-private per-bin regions (LDS cursors).
// Payload: (val[31:2]|r) << 32 | row<<16 | col.
// ---------------------------------------------------------------------------
__global__ __launch_bounds__(256)
void scatter_coarse(const int* __restrict__ rows, const int* __restrict__ cols,
                    const float* __restrict__ vals, const int* __restrict__ ctoffs,
                    u64* __restrict__ edc, int RE, int E, int Nn,
                    int chunk, int NBIN)
{
    __shared__ int lcur[800];
    const int blk = blockIdx.x;
    for (int i = threadIdx.x; i < NBIN; i += 256)
        lcur[i] = ctoffs[i * gridDim.x + blk];
    __syncthreads();
    const int e0 = blk * chunk;
    const int e1 = min(e0 + chunk, RE);
    for (int e = e0 + threadIdx.x; e < e1; e += 256) {
        const int r   = e / E;
        const int row = rows[e];
        const int wid = r * Nn + row;
        const int pos = atomicAdd(&lcur[wid >> 8], 1);
        const unsigned vb = __float_as_uint(vals[e]);
        edc[pos] = ((u64)((vb & 0xFFFFFFFCu) | (unsigned)r) << 32)
                 | ((unsigned)row << 16) | (unsigned)cols[e];
    }
}

// ---------------------------------------------------------------------------
// Fine scatter + fused edge-wise scores. One block per bin (256 wids).
// Pass 1: per-wid LDS counts -> LDS scan -> offs. Pass 2: place edges AND
// accumulate score[wid] += val*y[col][r] in LDS. Store SC with deg==0
// sentinel at the end (scores complete: every wid is in exactly one bin).
// ---------------------------------------------------------------------------
__global__ __launch_bounds__(256)
void scatter_fine(const u64* __restrict__ edc, const int* __restrict__ ctoffs,
                  int* __restrict__ offs, u64* __restrict__ edata,
                  const float* __restrict__ y, float* __restrict__ SC,
                  int RE, int Nn, int NB1, int NBIN)
{
    __shared__ int   cnt[256];
    __shared__ int   cur[256];
    __shared__ float scr[256];
    const int bin     = blockIdx.x;
    const int widbase = bin << 8;
    const int RN      = Nn << 2;
    const int t       = threadIdx.x;
    cnt[t] = 0;
    scr[t] = 0.f;
    __syncthreads();
    const int cs = ctoffs[bin * NB1];
    const int ce = (bin + 1 < NBIN) ? ctoffs[(bin + 1) * NB1] : RE;
    // pass 1: per-wid counts
    for (int j = cs + t; j < ce; j += 256) {
        const u64 p = edc[j];
        const unsigned hi = (unsigned)(p >> 32);
        const unsigned lo = (unsigned)p;
        const int w = (int)(hi & 3u) * Nn + (int)(lo >> 16);
        atomicAdd(&cnt[w - widbase], 1);
    }
    __syncthreads();
    // LDS exclusive scan of 256 counts
    const int v = cnt[t];
    cur[t] = v;
    __syncthreads();
    for (int off = 1; off < 256; off <<= 1) {
        const int x = (t >= off) ? cur[t - off] : 0;
        __syncthreads();
        cur[t] += x;
        __syncthreads();
    }
    const int excl = cur[t] - v;
    const int wid  = widbase + t;
    if (wid < RN) offs[wid] = cs + excl;
    __syncthreads();
    cur[t] = cs + excl;
    __syncthreads();
    // pass 2: place edges + accumulate scores
    for (int j = cs + t; j < ce; j += 256) {
        const u64 p  = edc[j];
        const unsigned hi = (unsigned)(p >> 32);
        const unsigned lo = (unsigned)p;
        const int r   = (int)(hi & 3u);
        const int col = (int)(lo & 0xFFFFu);
        const int w   = r * Nn + (int)(lo >> 16);
        const int pos = atomicAdd(&cur[w - widbase], 1);
        edata[pos] = ((u64)(hi & 0xFFFFFFFCu) << 32) | (unsigned)col;
        const float val = __uint_as_float(hi & 0xFFFFFFFCu);
        atomicAdd(&scr[w - widbase], val * y[(size_t)col * 4 + r]);
    }
    __syncthreads();
    if (wid < RN) {
        const int r = wid / Nn;
        const int n = wid - r * Nn;
        SC[(size_t)n * 4 + r] = (v > 0) ? scr[t] : -1e30f;
    }
}

// ---------------------------------------------------------------------------
// Per-node masked softmax over 4 relation scores.
// ---------------------------------------------------------------------------
__global__ __launch_bounds__(256)
void softmax4(const float* __restrict__ scores, float* __restrict__ attn, int Nn)
{
    const int n = blockIdx.x * 256 + threadIdx.x;
    if (n >= Nn) return;
    const float4 s4 = *reinterpret_cast<const float4*>(scores + (size_t)n * 4);
    float s[4] = { s4.x, s4.y, s4.z, s4.w };
    float mx = -3.0e38f;
#pragma unroll
    for (int r = 0; r < 4; ++r) mx = fmaxf(mx, s[r]);
    float ex[4], es = 0.f;
#pragma unroll
    for (int r = 0; r < 4; ++r) { ex[r] = expf(s[r] - mx); es += ex[r]; }
    const float inv = 1.0f / es;
    float4 o;
    o.x = (s[0] > -1e29f) ? ex[0] * inv : 0.0f;
    o.y = (s[1] > -1e29f) ? ex[1] * inv : 0.0f;
    o.z = (s[2] > -1e29f) ? ex[2] * inv : 0.0f;
    o.w = (s[3] > -1e29f) ? ex[3] * inv : 0.0f;
    *reinterpret_cast<float4*>(attn + (size_t)n * 4) = o;
}

// ---------------------------------------------------------------------------
// Aggregation: one wave per (r,n); half-waves process alternating edges.
// 4-deep pipeline: 4 edata loads then 4 independent 16B f16 gathers in
// flight per half-wave, packed hfma2 accumulation. Scaled bf16 nontemporal
// store.
// ---------------------------------------------------------------------------
__global__ __launch_bounds__(256)
void agg_csr(const int* __restrict__ offs, const u64* __restrict__ edata,
             const unsigned short* __restrict__ xh, const float* __restrict__ attn,
             unsigned short* __restrict__ agg, int Nn, int RE)
{
    const int wid  = (blockIdx.x << 2) + (threadIdx.x >> 6);
    const int lane = threadIdx.x & 63;
    const int half = lane >> 5;
    const int sub  = lane & 31;
    const int RN   = Nn << 2;
    if (wid >= RN) return;
    const int r = wid / Nn;
    const int n = wid - r * Nn;

    const int start = offs[wid];
    const int end   = (wid + 1 < RN) ? offs[wid + 1] : RE;

    __half2 acc0 = __float2half2_rn(0.f), acc1 = acc0, acc2 = acc0, acc3 = acc0;

    int j = start + half;
    for (; j + 6 < end; j += 8) {
        u64 e[4];
#pragma unroll
        for (int q = 0; q < 4; ++q)
            e[q] = __builtin_nontemporal_load(edata + j + 2 * q);
        uint4 d[4];
        __half2 vv[4];
#pragma unroll
        for (int q = 0; q < 4; ++q) {
            const int c = (int)(e[q] & 0xffffffffu);
            vv[q] = __float2half2_rn(__uint_as_float((unsigned)(e[q] >> 32)));
            d[q]  = *reinterpret_cast<const uint4*>(xh + ((size_t)c << 8) + sub * 8);
        }
#pragma unroll
        for (int q = 0; q < 4; ++q) {
            acc0 = __hfma2(vv[q], u2h2(d[q].x), acc0);
            acc1 = __hfma2(vv[q], u2h2(d[q].y), acc1);
            acc2 = __hfma2(vv[q], u2h2(d[q].z), acc2);
            acc3 = __hfma2(vv[q], u2h2(d[q].w), acc3);
        }
    }
    for (; j < end; j += 2) {
        const u64 e0 = __builtin_nontemporal_load(edata + j);
        const int c0 = (int)(e0 & 0xffffffffu);
        const __half2 v0 = __float2half2_rn(__uint_as_float((unsigned)(e0 >> 32)));
        const uint4 d0 = *reinterpret_cast<const uint4*>(xh + ((size_t)c0 << 8) + sub * 8);
        acc0 = __hfma2(v0, u2h2(d0.x), acc0);
        acc1 = __hfma2(v0, u2h2(d0.y), acc1);
        acc2 = __hfma2(v0, u2h2(d0.z), acc2);
        acc3 = __hfma2(v0, u2h2(d0.w), acc3);
    }

    float a[8];
    a[0] = __low2float(acc0); a[1] = __high2float(acc0);
    a[2] = __low2float(acc1); a[3] = __high2float(acc1);
    a[4] = __low2float(acc2); a[5] = __high2float(acc2);
    a[6] = __low2float(acc3); a[7] = __high2float(acc3);
#pragma unroll
    for (int i = 0; i < 8; ++i) a[i] += __shfl_xor(a[i], 32, 64);

    if (half == 0) {
        const float sc = attn[(size_t)n * 4 + r];
        u32x4 st;
        st.x = pack2(sc * a[0], sc * a[1]);
        st.y = pack2(sc * a[2], sc * a[3]);
        st.z = pack2(sc * a[4], sc * a[5]);
        st.w = pack2(sc * a[6], sc * a[7]);
        __builtin_nontemporal_store(
            st, reinterpret_cast<u32x4*>(agg + ((size_t)wid << 8) + sub * 8));
    }
}

// ---------------------------------------------------------------------------
extern "C" void kernel_launch(void* const* d_in, const int* in_sizes, int n_in,
                              void* d_out, int out_size, void* d_ws, size_t ws_size,
                              hipStream_t stream)
{
    const int*   rows     = (const int*)d_in[0];
    const int*   cols     = (const int*)d_in[1];
    const float* vals     = (const float*)d_in[2];
    const float* node_emb = (const float*)d_in[3];
    const float* pre_W    = (const float*)d_in[4];
    const float* pre_b    = (const float*)d_in[5];
    const float* ln1_g    = (const float*)d_in[6];
    const float* ln1_b    = (const float*)d_in[7];
    const float* rel_W    = (const float*)d_in[8];
    const float* attn_vec = (const float*)d_in[9];
    const float* self_W   = (const float*)d_in[10];
    const float* self_b   = (const float*)d_in[11];
    const float* bias     = (const float*)d_in[12];
    const float* ln2_g    = (const float*)d_in[13];
    const float* ln2_b    = (const float*)d_in[14];

    const int Dd = 256;
    const int R  = in_sizes[8] / (Dd * Dd);   // 4
    const int N  = in_sizes[3] / Dd;          // 50000
    const int E  = in_sizes[0] / R;           // 800000
    const int RE = R * E;                     // 3.2M
    const int RN = R * N;                     // 200000

    const int NB1   = 256;
    const int chunk = (RE + NB1 - 1) / NB1;   // 12500
    const int NBIN  = (RN + 255) / 256;       // 782
    const int NCT   = NBIN * NB1;             // 200192

    float* out  = (float*)d_out;
    float* outF = out;                              // final  [N][256] f32
    float* outA = out + (size_t)N * Dd;             // attn   [N][4]   f32
    float* outX = outA + (size_t)N * R;             // x_all  [N][256] f32

    char* wp = (char*)d_ws;
    auto alloc = [&](size_t bytes) {
        char* p = wp;
        wp += (bytes + 255) & ~(size_t)255;
        return p;
    };
    unsigned short* AGGS = (unsigned short*)alloc((size_t)RN * Dd * 2);   // 102.4 MB
    unsigned short* XB   = (unsigned short*)alloc((size_t)N * Dd * 2);    //  25.6 MB
    unsigned short* XH   = (unsigned short*)alloc((size_t)N * Dd * 2);    //  25.6 MB
    unsigned short* EMB  = (unsigned short*)alloc((size_t)N * Dd * 2);    //  25.6 MB
    unsigned short* BTm  = (unsigned short*)alloc((size_t)Dd * 1280 * 2); // 655 KB
    unsigned short* BTp  = (unsigned short*)alloc((size_t)Dd * Dd * 2);   // 131 KB
    float* WT   = (float*)alloc((size_t)R * Dd * 4);
    float* Y    = (float*)alloc((size_t)N * R * 4);
    float* SC   = (float*)alloc((size_t)N * R * 4);
    int* offs   = (int*)alloc((size_t)RN * 4);
    int* cnt_t  = (int*)alloc((size_t)NCT * 4);
    int* ctoffs = cnt_t;                            // scanned in place
    int* bsums2 = (int*)alloc(1024);
    u64* edata  = (u64*)alloc((size_t)RE * 8);      // 25.6 MB (fine)
    u64* edc    = (u64*)alloc((size_t)RE * 8);      // 25.6 MB (coarse)

    const int gblocks = (N + 127) / 128;            // 391
    const int nblkC   = (NCT + 1023) / 1024;        // 196

    // 1. B-matrix prep + emb conversion (+x_all passthrough)
    build_bt<<<(1280 * 256 + 256 * 256 + 255) / 256, 256, 0, stream>>>(
        rel_W, self_W, pre_W, BTm, BTp);
    conv_emb<<<2048, 256, 0, stream>>>(node_emb, EMB, outX, N * Dd / 4);

    // 2. pre-encoder -> X (bf16 + f16 copies)
    gemm_mfma<0><<<gblocks, 512, 0, stream>>>(EMB, nullptr, nullptr, nullptr, nullptr,
                                              BTp, pre_b, nullptr, ln1_g, ln1_b,
                                              nullptr, XB, XH, N);
    // 3. w~ and y
    wtilde_kernel<<<R, 256, 0, stream>>>(rel_W, attn_vec, WT);
    y_kernel<<<(N + 3) / 4, 256, 0, stream>>>(XB, WT, Y, N);

    // 4. CSR build (two-level; offs + scores derived in fine pass)
    hist_bin<<<NB1, 256, 0, stream>>>(rows, cnt_t, RE, E, N, chunk, NBIN);
    scan_blocks<<<nblkC, 256, 0, stream>>>(cnt_t, ctoffs, bsums2, NCT);
    scan_bsums<<<1, 256, 0, stream>>>(bsums2, nblkC);
    scan_add<<<(NCT + 255) / 256, 256, 0, stream>>>(ctoffs, bsums2, NCT);
    scatter_coarse<<<NB1, 256, 0, stream>>>(rows, cols, vals, ctoffs, edc,
                                            RE, E, N, chunk, NBIN);
    scatter_fine<<<NBIN, 256, 0, stream>>>(edc, ctoffs, offs, edata, Y, SC,
                                           RE, N, NB1, NBIN);

    // 5. masked softmax -> attn (outA)
    softmax4<<<(N + 255) / 256, 256, 0, stream>>>(SC, outA, N);

    // 6. aggregation with fused attn scaling (f16 gather, 4-deep pipeline)
    agg_csr<<<(RN + 3) / 4, 256, 0, stream>>>(offs, edata, XH, outA, AGGS, N, RE);

    // 7. mega-GEMM -> final (outF)
    gemm_mfma<1><<<gblocks, 512, 0, stream>>>(AGGS, AGGS + (size_t)N * Dd,
                                              AGGS + (size_t)2 * N * Dd,
                                              AGGS + (size_t)3 * N * Dd, XB,
                                              BTm, bias, self_b, ln2_g, ln2_b,
                                              outF, nullptr, nullptr, N);
}

// Round 12
// 538.478 us; speedup vs baseline: 1.5248x; 1.0401x over previous
//
#include <hip/hip_runtime.h>
#include <hip/hip_fp16.h>
#include <math.h>

// ---------------------------------------------------------------------------
// LearnableWeightedRGCN — round 12.
// Changes vs R11:
//  * edata records u32 (val_f16<<16 | col_u16): halves fine-scatter write and
//    agg's edata stream. val f16 adds ~0.05% rel error (negligible).
//  * y_kernel fused into pre-GEMM epilogue (LDS reduce reusing smA space).
//  * build_bt + wtilde merged into one prep kernel.
// agg_csr is L3-fabric-BW-bound (~3.4 TB/s, R11 MLP test flat) — only byte
// reduction helps it.
// ---------------------------------------------------------------------------

typedef __attribute__((ext_vector_type(8))) short bf16x8;
typedef __attribute__((ext_vector_type(4))) float f32x4;
typedef __attribute__((ext_vector_type(4))) unsigned u32x4;
typedef unsigned long long u64;

__device__ __forceinline__ float gelu_exact(float v) {
    return 0.5f * v * (1.0f + erff(v * 0.70710678118654752f));
}
__device__ __forceinline__ unsigned short f2bf(float f) {   // RNE
    unsigned u = __float_as_uint(f);
    return (unsigned short)((u + 0x7fffu + ((u >> 16) & 1u)) >> 16);
}
__device__ __forceinline__ unsigned pack2(float a, float b) {
    return (unsigned)f2bf(a) | ((unsigned)f2bf(b) << 16);
}
__device__ __forceinline__ unsigned short f2h(float f) {
    return __half_as_ushort(__float2half(f));
}
__device__ __forceinline__ __half2 u2h2(unsigned u) {
    union { unsigned u; __half2 h; } c; c.u = u; return c.h;
}
__device__ __forceinline__ void gload16(const void* g, void* l) {
    __builtin_amdgcn_global_load_lds(
        (const __attribute__((address_space(1))) void*)g,
        (__attribute__((address_space(3))) void*)l, 16, 0, 0);
}

// ---------------------------------------------------------------------------
// node_emb f32 -> bf16 EMB  +  f32 x_all passthrough (fused copy)
// ---------------------------------------------------------------------------
__global__ __launch_bounds__(256)
void conv_emb(const float* __restrict__ ne, unsigned short* __restrict__ emb,
              float* __restrict__ outX, int total4)
{
    const int stride = gridDim.x * blockDim.x;
    for (int i = blockIdx.x * blockDim.x + threadIdx.x; i < total4; i += stride) {
        const float4 v = reinterpret_cast<const float4*>(ne)[i];
        reinterpret_cast<float4*>(outX)[i] = v;
        ushort4 h;
        h.x = f2bf(v.x); h.y = f2bf(v.y); h.z = f2bf(v.z); h.w = f2bf(v.w);
        reinterpret_cast<ushort4*>(emb)[i] = h;
    }
}

// ---------------------------------------------------------------------------
// Prep: B-matrix conversion (blocks 0..1535) + w~ (blocks 1536..1539).
// ---------------------------------------------------------------------------
__global__ __launch_bounds__(256)
void prep_kernel(const float* __restrict__ relW, const float* __restrict__ selfW,
                 const float* __restrict__ preW, const float* __restrict__ av,
                 unsigned short* __restrict__ BTm, unsigned short* __restrict__ BTp,
                 float* __restrict__ wt)
{
    const int blk = blockIdx.x;
    if (blk < 1536) {
        const int idx = blk * 256 + threadIdx.x;
        if (idx < 1280 * 256) {
            const int k = idx >> 8, n = idx & 255;
            const float v = (k < 1024)
                ? relW[(size_t)(k >> 8) * 65536 + (size_t)(k & 255) * 256 + n]
                : selfW[(size_t)(k - 1024) * 256 + n];
            BTm[(size_t)n * 1280 + k] = f2bf(v);
        } else {
            const int i2 = idx - 1280 * 256;
            const int k = i2 >> 8, n = i2 & 255;
            BTp[(size_t)n * 256 + k] = f2bf(preW[(size_t)k * 256 + n]);
        }
    } else {
        __shared__ float avs[256];
        const int r = blk - 1536, tid = threadIdx.x;
        avs[tid] = av[tid];
        __syncthreads();
        const float* W = relW + (size_t)r * 65536 + (size_t)tid * 256;
        float s = 0.f;
        for (int j = 0; j < 256; j += 4) {
            const float4 w4 = *reinterpret_cast<const float4*>(W + j);
            s += w4.x * avs[j] + w4.y * avs[j + 1] + w4.z * avs[j + 2] + w4.w * avs[j + 3];
        }
        wt[r * 256 + tid] = s;
    }
}

// ---------------------------------------------------------------------------
// MFMA GEMM: BM=128, BN=256, BK=64, 512 threads (8 waves, 2m x 4n).
// MODE 0: X = gelu(LN1(EMB@pre_W + pre_b)) -> XOut (bf16) + XH (f16),
//         plus fused y[n][r] = x[n].w~[r] -> Yout (reuses smA as LDS scratch).
// MODE 1: final = LN2(gelu([agg|x]@[rel;self] + biases)) -> Cout (f32).
// ---------------------------------------------------------------------------
template<int MODE>
__global__ __launch_bounds__(512)
void gemm_mfma(const unsigned short* __restrict__ a0,
               const unsigned short* __restrict__ a1,
               const unsigned short* __restrict__ a2,
               const unsigned short* __restrict__ a3,
               const unsigned short* __restrict__ a4,
               const unsigned short* __restrict__ BT,
               const float* __restrict__ bias0, const float* __restrict__ bias1,
               const float* __restrict__ lng, const float* __restrict__ lnb,
               const float* __restrict__ wt, float* __restrict__ Yout,
               float* __restrict__ Cout, unsigned short* __restrict__ XOut,
               unsigned short* __restrict__ XH, int M)
{
    constexpr int K    = MODE ? 1280 : 256;
    constexpr int NSEG = MODE ? 5 : 1;

    __shared__ __align__(16) unsigned char smA[128 * 128];   // 16 KB
    __shared__ __align__(16) unsigned char smB[256 * 128];   // 32 KB
    __shared__ float redS[4][128];
    __shared__ float redQ[4][128];

    const int tid = threadIdx.x;
    const int w   = tid >> 6;
    const int l   = tid & 63;
    const int wm  = w >> 2, wn = w & 3;
    const int brow = blockIdx.x * 128;

    const int srow = l >> 3;
    const int sgA  = (l & 7) ^ srow;

    f32x4 acc[4][4];
#pragma unroll
    for (int mb = 0; mb < 4; ++mb)
#pragma unroll
        for (int nb = 0; nb < 4; ++nb)
            acc[mb][nb] = f32x4{0.f, 0.f, 0.f, 0.f};

    for (int seg = 0; seg < NSEG; ++seg) {
        const unsigned short* Abase =
            (MODE == 0) ? a0
                        : (seg == 0 ? a0 : seg == 1 ? a1 : seg == 2 ? a2
                                         : seg == 3 ? a3 : a4);
#pragma unroll
        for (int kk = 0; kk < 4; ++kk) {
            __syncthreads();
#pragma unroll
            for (int c = 0; c < 2; ++c) {
                const int r0 = (w * 2 + c) * 8;
                int gm = brow + r0 + srow;
                gm = min(gm, M - 1);
                gload16(Abase + ((size_t)gm << 8) + kk * 64 + sgA * 8,
                        smA + (w * 2 + c) * 1024);
            }
#pragma unroll
            for (int c = 0; c < 4; ++c) {
                const int bn = (w * 4 + c) * 8 + srow;
                gload16(BT + (size_t)bn * K + (seg * 4 + kk) * 64 + sgA * 8,
                        smB + (w * 4 + c) * 1024);
            }
            __syncthreads();

#pragma unroll
            for (int ks = 0; ks < 2; ++ks) {
                bf16x8 af[4], bf[4];
#pragma unroll
                for (int mb = 0; mb < 4; ++mb) {
                    const int row = wm * 64 + mb * 16 + (l & 15);
                    const int g   = (ks * 4 + (l >> 4)) ^ (row & 7);
                    af[mb] = *reinterpret_cast<const bf16x8*>(smA + row * 128 + g * 16);
                }
#pragma unroll
                for (int nb = 0; nb < 4; ++nb) {
                    const int row = wn * 64 + nb * 16 + (l & 15);
                    const int g   = (ks * 4 + (l >> 4)) ^ (row & 7);
                    bf[nb] = *reinterpret_cast<const bf16x8*>(smB + row * 128 + g * 16);
                }
#pragma unroll
                for (int mb = 0; mb < 4; ++mb)
#pragma unroll
                    for (int nb = 0; nb < 4; ++nb)
                        acc[mb][nb] = __builtin_amdgcn_mfma_f32_16x16x32_bf16(
                            af[mb], bf[nb], acc[mb][nb], 0, 0, 0);
            }
        }
    }

    // ---- epilogue ----
    float bb[4], gw[4], bw[4];
#pragma unroll
    for (int nb = 0; nb < 4; ++nb) {
        const int n = wn * 64 + nb * 16 + (l & 15);
        bb[nb] = bias0[n] + (MODE == 1 ? bias1[n] : 0.0f);
        gw[nb] = lng[n];
        bw[nb] = lnb[n];
    }
#pragma unroll
    for (int mb = 0; mb < 4; ++mb)
#pragma unroll
        for (int nb = 0; nb < 4; ++nb)
#pragma unroll
            for (int rg = 0; rg < 4; ++rg) {
                float v = acc[mb][nb][rg] + bb[nb];
                if (MODE == 1) v = gelu_exact(v);
                acc[mb][nb][rg] = v;
            }
#pragma unroll
    for (int mb = 0; mb < 4; ++mb)
#pragma unroll
        for (int rg = 0; rg < 4; ++rg) {
            float s = 0.f, q = 0.f;
#pragma unroll
            for (int nb = 0; nb < 4; ++nb) {
                const float v = acc[mb][nb][rg];
                s += v; q += v * v;
            }
#pragma unroll
            for (int off = 1; off < 16; off <<= 1) {
                s += __shfl_xor(s, off, 64);
                q += __shfl_xor(q, off, 64);
            }
            if ((l & 15) == 0) {
                const int row = wm * 64 + mb * 16 + (l >> 4) * 4 + rg;
                redS[wn][row] = s;
                redQ[wn][row] = q;
            }
        }
    __syncthreads();
    if (tid < 128) {
        const float s = redS[0][tid] + redS[1][tid] + redS[2][tid] + redS[3][tid];
        const float q = redQ[0][tid] + redQ[1][tid] + redQ[2][tid] + redQ[3][tid];
        const float mean = s * (1.0f / 256.0f);
        const float var  = q * (1.0f / 256.0f) - mean * mean;
        redS[0][tid] = mean;
        redQ[0][tid] = rsqrtf(var + 1e-5f);
    }
    __syncthreads();

    // yred reuses smA (A-tiles dead; barrier above separates): [wn][row] float4
    float4* yred = reinterpret_cast<float4*>(smA);

#pragma unroll
    for (int mb = 0; mb < 4; ++mb)
#pragma unroll
        for (int rg = 0; rg < 4; ++rg) {
            const int row = wm * 64 + mb * 16 + (l >> 4) * 4 + rg;
            const float mu = redS[0][row];
            const float rs = redQ[0][row];
            const bool rowok = (brow + row < M);
            float yp0 = 0.f, yp1 = 0.f, yp2 = 0.f, yp3 = 0.f;
#pragma unroll
            for (int nb = 0; nb < 4; ++nb) {
                const int n = wn * 64 + nb * 16 + (l & 15);
                const float v = (acc[mb][nb][rg] - mu) * rs * gw[nb] + bw[nb];
                if (MODE == 0) {
                    const float gv = gelu_exact(v);
                    if (rowok) {
                        XOut[((size_t)(brow + row) << 8) + n] = f2bf(gv);
                        XH[((size_t)(brow + row) << 8) + n]   = f2h(gv);
                    }
                    yp0 += gv * wt[n];
                    yp1 += gv * wt[256 + n];
                    yp2 += gv * wt[512 + n];
                    yp3 += gv * wt[768 + n];
                } else {
                    if (rowok) Cout[((size_t)(brow + row) << 8) + n] = v;
                }
            }
            if (MODE == 0) {
#pragma unroll
                for (int off = 1; off < 16; off <<= 1) {
                    yp0 += __shfl_xor(yp0, off, 64);
                    yp1 += __shfl_xor(yp1, off, 64);
                    yp2 += __shfl_xor(yp2, off, 64);
                    yp3 += __shfl_xor(yp3, off, 64);
                }
                if ((l & 15) == 0)
                    yred[wn * 128 + row] = make_float4(yp0, yp1, yp2, yp3);
            }
        }
    if (MODE == 0) {
        __syncthreads();
        if (tid < 128 && brow + tid < M) {
            const float4 a = yred[tid];
            const float4 b = yred[128 + tid];
            const float4 c = yred[256 + tid];
            const float4 d = yred[384 + tid];
            *reinterpret_cast<float4*>(Yout + (size_t)(brow + tid) * 4) =
                make_float4(a.x + b.x + c.x + d.x, a.y + b.y + c.y + d.y,
                            a.z + b.z + c.z + d.z, a.w + b.w + c.w + d.w);
        }
    }
}

// ---------------------------------------------------------------------------
// Bin histogram (per-(block,bin) counts for the coarse scatter).
// ---------------------------------------------------------------------------
__global__ __launch_bounds__(256)
void hist_bin(const int* __restrict__ rows, int* __restrict__ cnt_t,
              int RE, int E, int Nn, int chunk, int NBIN)
{
    __shared__ int lh[800];
    const int blk = blockIdx.x;
    for (int i = threadIdx.x; i < NBIN; i += 256) lh[i] = 0;
    __syncthreads();
    const int e0 = blk * chunk;
    const int e1 = min(e0 + chunk, RE);
    for (int e = e0 + threadIdx.x; e < e1; e += 256) {
        const int r   = e / E;
        const int wid = r * Nn + rows[e];
        atomicAdd(&lh[wid >> 8], 1);
    }
    __syncthreads();
    for (int i = threadIdx.x; i < NBIN; i += 256)
        cnt_t[i * gridDim.x + blk] = lh[i];
}

// ---------------------------------------------------------------------------
// Exclusive scan (generic)
// ---------------------------------------------------------------------------
__global__ __launch_bounds__(256)
void scan_blocks(const int* __restrict__ counts, int* __restrict__ offs,
                 int* __restrict__ bsums, int n)
{
    __shared__ int sh[256];
    const int t = threadIdx.x;
    const int base = blockIdx.x * 1024 + t * 4;
    int v[4], s = 0;
#pragma unroll
    for (int j = 0; j < 4; ++j) {
        v[j] = (base + j < n) ? counts[base + j] : 0;
        s += v[j];
    }
    sh[t] = s;
    __syncthreads();
    for (int off = 1; off < 256; off <<= 1) {
        const int x = (t >= off) ? sh[t - off] : 0;
        __syncthreads();
        sh[t] += x;
        __syncthreads();
    }
    int run = sh[t] - s;
    if (t == 255) bsums[blockIdx.x] = sh[255];
#pragma unroll
    for (int j = 0; j < 4; ++j) {
        if (base + j < n) offs[base + j] = run;
        run += v[j];
    }
}

__global__ __launch_bounds__(256)
void scan_bsums(int* __restrict__ bsums, int nblk)
{
    __shared__ int sh[256];
    const int t = threadIdx.x;
    const int v = (t < nblk) ? bsums[t] : 0;
    sh[t] = v;
    __syncthreads();
    for (int off = 1; off < 256; off <<= 1) {
        const int x = (t >= off) ? sh[t - off] : 0;
        __syncthreads();
        sh[t] += x;
        __syncthreads();
    }
    if (t < nblk) bsums[t] = sh[t] - v;
}

__global__ __launch_bounds__(256)
void scan_add(int* __restrict__ offs, const int* __restrict__ bsums, int n)
{
    const int i = blockIdx.x * 256 + threadIdx.x;
    if (i >= n) return;
    offs[i] += bsums[i >> 10];
}

// ---------------------------------------------------------------------------
// Coarse scatter: edges -> block-private per-bin regions (LDS cursors).
// Payload: (val[31:2]|r) << 32 | row<<16 | col.
// ---------------------------------------------------------------------------
__global__ __launch_bounds__(256)
void scatter_coarse(const int* __restrict__ rows, const int* __restrict__ cols,
                    const float* __restrict__ vals, const int* __restrict__ ctoffs,
                    u64* __restrict__ edc, int RE, int E, int Nn,
                    int chunk, int NBIN)
{
    __shared__ int lcur[800];
    const int blk = blockIdx.x;
    for (int i = threadIdx.x; i < NBIN; i += 256)
        lcur[i] = ctoffs[i * gridDim.x + blk];
    __syncthreads();
    const int e0 = blk * chunk;
    const int e1 = min(e0 + chunk, RE);
    for (int e = e0 + threadIdx.x; e < e1; e += 256) {
        const int r   = e / E;
        const int row = rows[e];
        const int wid = r * Nn + row;
        const int pos = atomicAdd(&lcur[wid >> 8], 1);
        const unsigned vb = __float_as_uint(vals[e]);
        edc[pos] = ((u64)((vb & 0xFFFFFFFCu) | (unsigned)r) << 32)
                 | ((unsigned)row << 16) | (unsigned)cols[e];
    }
}

// ---------------------------------------------------------------------------
// Fine scatter + fused edge-wise scores. One block per bin (256 wids).
// Pass 1: per-wid LDS counts -> LDS scan -> offs. Pass 2: place edges (u32:
// val_f16<<16 | col) AND accumulate score[wid] += val*y[col][r] in LDS.
// ---------------------------------------------------------------------------
__global__ __launch_bounds__(256)
void scatter_fine(const u64* __restrict__ edc, const int* __restrict__ ctoffs,
                  int* __restrict__ offs, unsigned* __restrict__ edata,
                  const float* __restrict__ y, float* __restrict__ SC,
                  int RE, int Nn, int NB1, int NBIN)
{
    __shared__ int   cnt[256];
    __shared__ int   cur[256];
    __shared__ float scr[256];
    const int bin     = blockIdx.x;
    const int widbase = bin << 8;
    const int RN      = Nn << 2;
    const int t       = threadIdx.x;
    cnt[t] = 0;
    scr[t] = 0.f;
    __syncthreads();
    const int cs = ctoffs[bin * NB1];
    const int ce = (bin + 1 < NBIN) ? ctoffs[(bin + 1) * NB1] : RE;
    // pass 1: per-wid counts
    for (int j = cs + t; j < ce; j += 256) {
        const u64 p = edc[j];
        const unsigned hi = (unsigned)(p >> 32);
        const unsigned lo = (unsigned)p;
        const int w = (int)(hi & 3u) * Nn + (int)(lo >> 16);
        atomicAdd(&cnt[w - widbase], 1);
    }
    __syncthreads();
    // LDS exclusive scan of 256 counts
    const int v = cnt[t];
    cur[t] = v;
    __syncthreads();
    for (int off = 1; off < 256; off <<= 1) {
        const int x = (t >= off) ? cur[t - off] : 0;
        __syncthreads();
        cur[t] += x;
        __syncthreads();
    }
    const int excl = cur[t] - v;
    const int wid  = widbase + t;
    if (wid < RN) offs[wid] = cs + excl;
    __syncthreads();
    cur[t] = cs + excl;
    __syncthreads();
    // pass 2: place edges (u32) + accumulate scores
    for (int j = cs + t; j < ce; j += 256) {
        const u64 p  = edc[j];
        const unsigned hi = (unsigned)(p >> 32);
        const unsigned lo = (unsigned)p;
        const int r   = (int)(hi & 3u);
        const int col = (int)(lo & 0xFFFFu);
        const int w   = r * Nn + (int)(lo >> 16);
        const int pos = atomicAdd(&cur[w - widbase], 1);
        const float val = __uint_as_float(hi & 0xFFFFFFFCu);
        edata[pos] = ((unsigned)f2h(val) << 16) | (unsigned)col;
        atomicAdd(&scr[w - widbase], val * y[(size_t)col * 4 + r]);
    }
    __syncthreads();
    if (wid < RN) {
        const int r = wid / Nn;
        const int n = wid - r * Nn;
        SC[(size_t)n * 4 + r] = (v > 0) ? scr[t] : -1e30f;
    }
}

// ---------------------------------------------------------------------------
// Per-node masked softmax over 4 relation scores.
// ---------------------------------------------------------------------------
__global__ __launch_bounds__(256)
void softmax4(const float* __restrict__ scores, float* __restrict__ attn, int Nn)
{
    const int n = blockIdx.x * 256 + threadIdx.x;
    if (n >= Nn) return;
    const float4 s4 = *reinterpret_cast<const float4*>(scores + (size_t)n * 4);
    float s[4] = { s4.x, s4.y, s4.z, s4.w };
    float mx = -3.0e38f;
#pragma unroll
    for (int r = 0; r < 4; ++r) mx = fmaxf(mx, s[r]);
    float ex[4], es = 0.f;
#pragma unroll
    for (int r = 0; r < 4; ++r) { ex[r] = expf(s[r] - mx); es += ex[r]; }
    const float inv = 1.0f / es;
    float4 o;
    o.x = (s[0] > -1e29f) ? ex[0] * inv : 0.0f;
    o.y = (s[1] > -1e29f) ? ex[1] * inv : 0.0f;
    o.z = (s[2] > -1e29f) ? ex[2] * inv : 0.0f;
    o.w = (s[3] > -1e29f) ? ex[3] * inv : 0.0f;
    *reinterpret_cast<float4*>(attn + (size_t)n * 4) = o;
}

// ---------------------------------------------------------------------------
// Aggregation: one wave per (r,n); half-waves process alternating edges.
// u32 edge records (val_f16 | col), 4-deep gather pipeline, packed hfma2,
// scaled bf16 nontemporal store.
// ---------------------------------------------------------------------------
__global__ __launch_bounds__(256)
void agg_csr(const int* __restrict__ offs, const unsigned* __restrict__ edata,
             const unsigned short* __restrict__ xh, const float* __restrict__ attn,
             unsigned short* __restrict__ agg, int Nn, int RE)
{
    const int wid  = (blockIdx.x << 2) + (threadIdx.x >> 6);
    const int lane = threadIdx.x & 63;
    const int half = lane >> 5;
    const int sub  = lane & 31;
    const int RN   = Nn << 2;
    if (wid >= RN) return;
    const int r = wid / Nn;
    const int n = wid - r * Nn;

    const int start = offs[wid];
    const int end   = (wid + 1 < RN) ? offs[wid + 1] : RE;

    __half2 acc0 = __float2half2_rn(0.f), acc1 = acc0, acc2 = acc0, acc3 = acc0;

    int j = start + half;
    for (; j + 6 < end; j += 8) {
        unsigned e[4];
#pragma unroll
        for (int q = 0; q < 4; ++q)
            e[q] = __builtin_nontemporal_load(edata + j + 2 * q);
        uint4 d[4];
        __half2 vv[4];
#pragma unroll
        for (int q = 0; q < 4; ++q) {
            const int c = (int)(e[q] & 0xFFFFu);
            const __half hv = __ushort_as_half((unsigned short)(e[q] >> 16));
            vv[q] = __half2half2(hv);
            d[q]  = *reinterpret_cast<const uint4*>(xh + ((size_t)c << 8) + sub * 8);
        }
#pragma unroll
        for (int q = 0; q < 4; ++q) {
            acc0 = __hfma2(vv[q], u2h2(d[q].x), acc0);
            acc1 = __hfma2(vv[q], u2h2(d[q].y), acc1);
            acc2 = __hfma2(vv[q], u2h2(d[q].z), acc2);
            acc3 = __hfma2(vv[q], u2h2(d[q].w), acc3);
        }
    }
    for (; j < end; j += 2) {
        const unsigned e0 = __builtin_nontemporal_load(edata + j);
        const int c0 = (int)(e0 & 0xFFFFu);
        const __half hv = __ushort_as_half((unsigned short)(e0 >> 16));
        const __half2 v0 = __half2half2(hv);
        const uint4 d0 = *reinterpret_cast<const uint4*>(xh + ((size_t)c0 << 8) + sub * 8);
        acc0 = __hfma2(v0, u2h2(d0.x), acc0);
        acc1 = __hfma2(v0, u2h2(d0.y), acc1);
        acc2 = __hfma2(v0, u2h2(d0.z), acc2);
        acc3 = __hfma2(v0, u2h2(d0.w), acc3);
    }

    float a[8];
    a[0] = __low2float(acc0); a[1] = __high2float(acc0);
    a[2] = __low2float(acc1); a[3] = __high2float(acc1);
    a[4] = __low2float(acc2); a[5] = __high2float(acc2);
    a[6] = __low2float(acc3); a[7] = __high2float(acc3);
#pragma unroll
    for (int i = 0; i < 8; ++i) a[i] += __shfl_xor(a[i], 32, 64);

    if (half == 0) {
        const float sc = attn[(size_t)n * 4 + r];
        u32x4 st;
        st.x = pack2(sc * a[0], sc * a[1]);
        st.y = pack2(sc * a[2], sc * a[3]);
        st.z = pack2(sc * a[4], sc * a[5]);
        st.w = pack2(sc * a[6], sc * a[7]);
        __builtin_nontemporal_store(
            st, reinterpret_cast<u32x4*>(agg + ((size_t)wid << 8) + sub * 8));
    }
}

// ---------------------------------------------------------------------------
extern "C" void kernel_launch(void* const* d_in, const int* in_sizes, int n_in,
                              void* d_out, int out_size, void* d_ws, size_t ws_size,
                              hipStream_t stream)
{
    const int*   rows     = (const int*)d_in[0];
    const int*   cols     = (const int*)d_in[1];
    const float* vals     = (const float*)d_in[2];
    const float* node_emb = (const float*)d_in[3];
    const float* pre_W    = (const float*)d_in[4];
    const float* pre_b    = (const float*)d_in[5];
    const float* ln1_g    = (const float*)d_in[6];
    const float* ln1_b    = (const float*)d_in[7];
    const float* rel_W    = (const float*)d_in[8];
    const float* attn_vec = (const float*)d_in[9];
    const float* self_W   = (const float*)d_in[10];
    const float* self_b   = (const float*)d_in[11];
    const float* bias     = (const float*)d_in[12];
    const float* ln2_g    = (const float*)d_in[13];
    const float* ln2_b    = (const float*)d_in[14];

    const int Dd = 256;
    const int R  = in_sizes[8] / (Dd * Dd);   // 4
    const int N  = in_sizes[3] / Dd;          // 50000
    const int E  = in_sizes[0] / R;           // 800000
    const int RE = R * E;                     // 3.2M
    const int RN = R * N;                     // 200000

    const int NB1   = 256;
    const int chunk = (RE + NB1 - 1) / NB1;   // 12500
    const int NBIN  = (RN + 255) / 256;       // 782
    const int NCT   = NBIN * NB1;             // 200192

    float* out  = (float*)d_out;
    float* outF = out;                              // final  [N][256] f32
    float* outA = out + (size_t)N * Dd;             // attn   [N][4]   f32
    float* outX = outA + (size_t)N * R;             // x_all  [N][256] f32

    char* wp = (char*)d_ws;
    auto alloc = [&](size_t bytes) {
        char* p = wp;
        wp += (bytes + 255) & ~(size_t)255;
        return p;
    };
    unsigned short* AGGS = (unsigned short*)alloc((size_t)RN * Dd * 2);   // 102.4 MB
    unsigned short* XB   = (unsigned short*)alloc((size_t)N * Dd * 2);    //  25.6 MB
    unsigned short* XH   = (unsigned short*)alloc((size_t)N * Dd * 2);    //  25.6 MB
    unsigned short* EMB  = (unsigned short*)alloc((size_t)N * Dd * 2);    //  25.6 MB
    unsigned short* BTm  = (unsigned short*)alloc((size_t)Dd * 1280 * 2); // 655 KB
    unsigned short* BTp  = (unsigned short*)alloc((size_t)Dd * Dd * 2);   // 131 KB
    float* WT   = (float*)alloc((size_t)R * Dd * 4);
    float* Y    = (float*)alloc((size_t)N * R * 4);
    float* SC   = (float*)alloc((size_t)N * R * 4);
    int* offs   = (int*)alloc((size_t)RN * 4);
    int* cnt_t  = (int*)alloc((size_t)NCT * 4);
    int* ctoffs = cnt_t;                            // scanned in place
    int* bsums2 = (int*)alloc(1024);
    unsigned* edata = (unsigned*)alloc((size_t)RE * 4);  // 12.8 MB (fine, u32)
    u64* edc    = (u64*)alloc((size_t)RE * 8);           // 25.6 MB (coarse)

    const int gblocks = (N + 127) / 128;            // 391
    const int nblkC   = (NCT + 1023) / 1024;        // 196

    // 1. prep (B-matrices + w~) + emb conversion (+x_all passthrough)
    prep_kernel<<<1540, 256, 0, stream>>>(rel_W, self_W, pre_W, attn_vec,
                                          BTm, BTp, WT);
    conv_emb<<<2048, 256, 0, stream>>>(node_emb, EMB, outX, N * Dd / 4);

    // 2. pre-encoder -> X (bf16 + f16) + fused y
    gemm_mfma<0><<<gblocks, 512, 0, stream>>>(EMB, nullptr, nullptr, nullptr, nullptr,
                                              BTp, pre_b, nullptr, ln1_g, ln1_b,
                                              WT, Y, nullptr, XB, XH, N);

    // 3. CSR build (two-level; offs + scores derived in fine pass)
    hist_bin<<<NB1, 256, 0, stream>>>(rows, cnt_t, RE, E, N, chunk, NBIN);
    scan_blocks<<<nblkC, 256, 0, stream>>>(cnt_t, ctoffs, bsums2, NCT);
    scan_bsums<<<1, 256, 0, stream>>>(bsums2, nblkC);
    scan_add<<<(NCT + 255) / 256, 256, 0, stream>>>(ctoffs, bsums2, NCT);
    scatter_coarse<<<NB1, 256, 0, stream>>>(rows, cols, vals, ctoffs, edc,
                                            RE, E, N, chunk, NBIN);
    scatter_fine<<<NBIN, 256, 0, stream>>>(edc, ctoffs, offs, edata, Y, SC,
                                           RE, N, NB1, NBIN);

    // 4. masked softmax -> attn (outA)
    softmax4<<<(N + 255) / 256, 256, 0, stream>>>(SC, outA, N);

    // 5. aggregation with fused attn scaling (f16 gather, 4-deep pipeline)
    agg_csr<<<(RN + 3) / 4, 256, 0, stream>>>(offs, edata, XH, outA, AGGS, N, RE);

    // 6. mega-GEMM -> final (outF)
    gemm_mfma<1><<<gblocks, 512, 0, stream>>>(AGGS, AGGS + (size_t)N * Dd,
                                              AGGS + (size_t)2 * N * Dd,
                                              AGGS + (size_t)3 * N * Dd, XB,
                                              BTm, bias, self_b, ln2_g, ln2_b,
                                              nullptr, nullptr,
                                              outF, nullptr, nullptr, N);
}